// Round 5
// baseline (16468.677 us; speedup 1.0000x reference)
//
#include <hip/hip_runtime.h>
#include <math.h>

#define VSZ 50000
#define OOVN 50
#define VE 50050
#define EMB 256
#define HE 512
#define HD 512
#define NB 32
#define SRC 400
#define TDD 30
#define G3 1536   // 3*HE = 3*HD
#define FSCAN_NBLK 128

__device__ __forceinline__ float sigmf(float x) { return 1.f / (1.f + expf(-x)); }

// out[c*rows + r] = in[r*cols + c]
__global__ __launch_bounds__(256) void transpose_kernel(const float* __restrict__ in,
                                                        float* __restrict__ out,
                                                        int rows, int cols) {
    int idx = blockIdx.x * 256 + threadIdx.x;
    if (idx >= rows * cols) return;
    int r = idx / cols, c = idx % cols;
    out[c * rows + r] = in[idx];
}

// gi[(s*NB+n)*G3 + c] = bih[c] + sum_e embed[ids[n*steps+s]][e] * WihT[e*G3+c]
__global__ __launch_bounds__(256) void gi_kernel(const int* __restrict__ ids,
                                                 const float* __restrict__ embed,
                                                 const float* __restrict__ WihT,
                                                 const float* __restrict__ bih,
                                                 float* __restrict__ gi, int steps) {
    __shared__ float sx[16][EMB];
    __shared__ int stok[16];
    int tid = threadIdx.x;
    int g0 = blockIdx.x * 16;
    if (tid < 16) {
        int row = g0 + tid;
        int s = row / NB, n = row % NB;
        stok[tid] = ids[n * steps + s];
    }
    __syncthreads();
    for (int r = 0; r < 16; ++r) sx[r][tid] = embed[(size_t)stok[r] * EMB + tid];
    __syncthreads();
    int c = blockIdx.y * 256 + tid;
    float b = bih[c];
    float acc[16];
#pragma unroll
    for (int r = 0; r < 16; ++r) acc[r] = b;
    for (int e = 0; e < EMB; e += 4) {
        float w0 = WihT[(size_t)(e + 0) * G3 + c];
        float w1 = WihT[(size_t)(e + 1) * G3 + c];
        float w2 = WihT[(size_t)(e + 2) * G3 + c];
        float w3 = WihT[(size_t)(e + 3) * G3 + c];
#pragma unroll
        for (int r = 0; r < 16; ++r) {
            float4 x4 = *(const float4*)&sx[r][e];
            acc[r] += x4.x * w0 + x4.y * w1 + x4.z * w2 + x4.w * w3;
        }
    }
#pragma unroll
    for (int r = 0; r < 16; ++r) gi[(size_t)(g0 + r) * G3 + c] = acc[r];
}

// ---- one GRU phase of the fused scan. MODE: 0=fwd(enc z=0), 1=bwd(enc z=1), 2=dec ----
template <int MODE>
__device__ __forceinline__ void gru_phase(
    const float* __restrict__ hin,     // bypass-read h_{t-1}
    const float* __restrict__ gibase,  // gi + (s*NB)*G3
    const float* __restrict__ Whh,
    float bR, float bZ, float bN,
    float* __restrict__ hout,          // bypass-store target
    float* __restrict__ aux,           // MODE 0/1: enc ; MODE 2: hD_all row (normal store)
    int s,
    float* __restrict__ hlds,
    int tid, int jl, int kh, int ng, int j) {
    // gi prefetch (32 threads, 12 scattered loads each) — issued first, hides under staging
    float gpre[12];
    if (kh == 0) {
#pragma unroll
        for (int r = 0; r < 4; ++r) {
            const float* gir = gibase + (size_t)(ng * 4 + r) * G3 + j;
            gpre[r * 3 + 0] = gir[0];
            gpre[r * 3 + 1] = gir[512];
            gpre[r * 3 + 2] = gir[1024];
        }
    }
    // weights (L1/L2-hot, same addresses every step)
    float4 wreg[3][8];
#pragma unroll
    for (int g = 0; g < 3; ++g) {
        const float* wp = Whh + (size_t)(g * 512 + j) * 512 + kh * 32;
#pragma unroll
        for (int i = 0; i < 8; ++i) wreg[g][i] = *(const float4*)&wp[i * 4];
    }
    // stage h[32][512] via 8B bypass loads -> chunk-padded LDS
    const unsigned long long* hin8 = (const unsigned long long*)hin;
    for (int idx = tid; idx < 32 * 256; idx += 512) {
        unsigned long long uv = __hip_atomic_load(&hin8[idx], __ATOMIC_RELAXED,
                                                  __HIP_MEMORY_SCOPE_AGENT);
        union { unsigned long long u; float f[2]; } cv; cv.u = uv;
        int nn = idx >> 8, kk = (idx & 255) << 1;
        int off = nn * 576 + (kk >> 5) * 36 + (kk & 31);
        hlds[off] = cv.f[0];
        hlds[off + 1] = cv.f[1];
    }
    __syncthreads();

    float aR[4] = {0.f, 0.f, 0.f, 0.f};
    float aZ[4] = {0.f, 0.f, 0.f, 0.f};
    float aN[4] = {0.f, 0.f, 0.f, 0.f};
    const int kbase = kh * 36;
    const float* h0p = &hlds[(ng * 4 + 0) * 576 + kbase];
    const float* h1p = &hlds[(ng * 4 + 1) * 576 + kbase];
    const float* h2p = &hlds[(ng * 4 + 2) * 576 + kbase];
    const float* h3p = &hlds[(ng * 4 + 3) * 576 + kbase];
#pragma unroll
    for (int i = 0; i < 8; ++i) {
        float4 wr = wreg[0][i], wz = wreg[1][i], wn = wreg[2][i];
        float4 ha = *(const float4*)&h0p[i * 4];
        float4 hb = *(const float4*)&h1p[i * 4];
        float4 hc = *(const float4*)&h2p[i * 4];
        float4 hd = *(const float4*)&h3p[i * 4];
        aR[0] += ha.x*wr.x + ha.y*wr.y + ha.z*wr.z + ha.w*wr.w;
        aZ[0] += ha.x*wz.x + ha.y*wz.y + ha.z*wz.z + ha.w*wz.w;
        aN[0] += ha.x*wn.x + ha.y*wn.y + ha.z*wn.z + ha.w*wn.w;
        aR[1] += hb.x*wr.x + hb.y*wr.y + hb.z*wr.z + hb.w*wr.w;
        aZ[1] += hb.x*wz.x + hb.y*wz.y + hb.z*wz.z + hb.w*wz.w;
        aN[1] += hb.x*wn.x + hb.y*wn.y + hb.z*wn.z + hb.w*wn.w;
        aR[2] += hc.x*wr.x + hc.y*wr.y + hc.z*wr.z + hc.w*wr.w;
        aZ[2] += hc.x*wz.x + hc.y*wz.y + hc.z*wz.z + hc.w*wz.w;
        aN[2] += hc.x*wn.x + hc.y*wn.y + hc.z*wn.z + hc.w*wn.w;
        aR[3] += hd.x*wr.x + hd.y*wr.y + hd.z*wr.z + hd.w*wr.w;
        aZ[3] += hd.x*wz.x + hd.y*wz.y + hd.z*wz.z + hd.w*wz.w;
        aN[3] += hd.x*wn.x + hd.y*wn.y + hd.z*wn.z + hd.w*wn.w;
    }
#pragma unroll
    for (int r = 0; r < 4; ++r) {
        aR[r] += __shfl_xor(aR[r], 4);  aR[r] += __shfl_xor(aR[r], 8);
        aR[r] += __shfl_xor(aR[r], 16); aR[r] += __shfl_xor(aR[r], 32);
        aZ[r] += __shfl_xor(aZ[r], 4);  aZ[r] += __shfl_xor(aZ[r], 8);
        aZ[r] += __shfl_xor(aZ[r], 16); aZ[r] += __shfl_xor(aZ[r], 32);
        aN[r] += __shfl_xor(aN[r], 4);  aN[r] += __shfl_xor(aN[r], 8);
        aN[r] += __shfl_xor(aN[r], 16); aN[r] += __shfl_xor(aN[r], 32);
    }
    if (kh == 0) {
#pragma unroll
        for (int r = 0; r < 4; ++r) {
            int n = ng * 4 + r;
            float rr  = sigmf(gpre[r * 3 + 0] + bR + aR[r]);
            float zz  = sigmf(gpre[r * 3 + 1] + bZ + aZ[r]);
            float nn2 = tanhf(gpre[r * 3 + 2] + bN + rr * aN[r]);
            float hp  = hlds[n * 576 + (j >> 5) * 36 + (j & 31)];
            float hnew = (1.f - zz) * nn2 + zz * hp;
            __hip_atomic_store(&hout[n * 512 + j], hnew, __ATOMIC_RELAXED,
                               __HIP_MEMORY_SCOPE_AGENT);
            if (MODE == 0)      aux[(size_t)(n * SRC + s) * 1024 + j] = hnew;
            else if (MODE == 1) aux[(size_t)(n * SRC + s) * 1024 + 512 + j] = hnew;
            else                aux[n * 512 + j] = hnew;   // hD_all (normal store)
        }
    }
    __syncthreads();   // drains all waves' stores before caller's flag store
}

// ---- fused persistent scan: fwd + bwd + dec interleaved; barrier latency hidden ----
// 128 blocks x 512 thr (1/CU). Per step: F phase, flag; B phase, flag; D phase (t<30),
// flag; THEN poll step-t flags of all chains (set ~2 phases ago -> near-zero wait).
__global__ __launch_bounds__(512) void fused_scan_kernel(
    const float* __restrict__ giF, const float* __restrict__ giB,
    const float* __restrict__ giD,
    const float* __restrict__ WhhF, const float* __restrict__ WhhB,
    const float* __restrict__ WhhD,
    const float* __restrict__ bhhF, const float* __restrict__ bhhB,
    const float* __restrict__ bhhD,
    float* __restrict__ hF0, float* __restrict__ hF1,
    float* __restrict__ hB0, float* __restrict__ hB1,
    float* __restrict__ h0d, float* __restrict__ hDs,
    float* __restrict__ hD_all, float* __restrict__ enc,
    unsigned int* __restrict__ flags) {
    const int bid = blockIdx.x;
    const int j0 = bid * 4;
    __shared__ float hlds[32 * 576];   // 73.7 KB
    const int tid = threadIdx.x;
    const int jl = tid & 3;
    const int kh = (tid >> 2) & 15;
    const int ng = tid >> 6;
    const int j  = j0 + jl;

    const float bFR = bhhF[j], bFZ = bhhF[512 + j], bFN = bhhF[1024 + j];
    const float bBR = bhhB[j], bBZ = bhhB[512 + j], bBN = bhhB[1024 + j];
    const float bDR = bhhD[j], bDZ = bhhD[512 + j], bDN = bhhD[1024 + j];

    for (int t = 0; t < SRC; ++t) {
        // ---- forward ----
        gru_phase<0>((t & 1) ? hF1 : hF0, giF + (size_t)t * NB * G3, WhhF,
                     bFR, bFZ, bFN, (t & 1) ? hF0 : hF1, enc, t,
                     hlds, tid, jl, kh, ng, j);
        if (tid == 0)
            __hip_atomic_store(&flags[(size_t)t * 128 + bid], 1u,
                               __ATOMIC_RELAXED, __HIP_MEMORY_SCOPE_AGENT);
        // ---- backward ----
        {
            int sb = SRC - 1 - t;
            gru_phase<1>((t & 1) ? hB1 : hB0, giB + (size_t)sb * NB * G3, WhhB,
                         bBR, bBZ, bBN, (t & 1) ? hB0 : hB1, enc, sb,
                         hlds, tid, jl, kh, ng, j);
            if (tid == 0)
                __hip_atomic_store(&flags[(size_t)(SRC + t) * 128 + bid], 1u,
                                   __ATOMIC_RELAXED, __HIP_MEMORY_SCOPE_AGENT);
        }
        // ---- decoder (first TDD steps only) ----
        if (t < TDD) {
            gru_phase<2>(t ? (hDs + (size_t)(t - 1) * NB * 512) : h0d,
                         giD + (size_t)t * NB * G3, WhhD,
                         bDR, bDZ, bDN, hDs + (size_t)t * NB * 512,
                         hD_all + (size_t)t * NB * 512, 0,
                         hlds, tid, jl, kh, ng, j);
            if (tid == 0)
                __hip_atomic_store(&flags[(size_t)(2 * SRC + t) * 128 + bid], 1u,
                                   __ATOMIC_RELAXED, __HIP_MEMORY_SCOPE_AGENT);
        }
        // ---- poll all chains' step-t flags (stale by 1-2 phases -> usually instant) ----
        if (t != SRC - 1) {
            if (tid < 64) {
                const unsigned int* fF = flags + (size_t)t * 128;
                const unsigned int* fB = flags + (size_t)(SRC + t) * 128;
                const unsigned int* fD = flags + (size_t)(2 * SRC + t) * 128;
                const int pd = (t < TDD);
                for (;;) {
                    unsigned int a = __hip_atomic_load(&fF[tid], __ATOMIC_RELAXED, __HIP_MEMORY_SCOPE_AGENT)
                                   & __hip_atomic_load(&fF[64 + tid], __ATOMIC_RELAXED, __HIP_MEMORY_SCOPE_AGENT)
                                   & __hip_atomic_load(&fB[tid], __ATOMIC_RELAXED, __HIP_MEMORY_SCOPE_AGENT)
                                   & __hip_atomic_load(&fB[64 + tid], __ATOMIC_RELAXED, __HIP_MEMORY_SCOPE_AGENT);
                    if (pd) {
                        a &= __hip_atomic_load(&fD[tid], __ATOMIC_RELAXED, __HIP_MEMORY_SCOPE_AGENT)
                           & __hip_atomic_load(&fD[64 + tid], __ATOMIC_RELAXED, __HIP_MEMORY_SCOPE_AGENT);
                    }
                    if (__all(a != 0u)) break;
                    __builtin_amdgcn_s_sleep(1);
                }
            }
            __syncthreads();
        }
    }
}

// key_proj J=2: kp[row*512 + c] = sum_k enc[row][k]*Wk[k*512+c]; 8 rows/block, grid 1600
__global__ __launch_bounds__(256) void keyproj_kernel(const float* __restrict__ enc,
                                                      const float* __restrict__ Wk,
                                                      float* __restrict__ kp) {
    __shared__ float sx[8][1024];
    int tid = threadIdx.x;
    int g0 = blockIdx.x * 8;
    for (int i = tid; i < 8 * 1024; i += 256)
        sx[i >> 10][i & 1023] = enc[(size_t)(g0 + (i >> 10)) * 1024 + (i & 1023)];
    __syncthreads();
    int c = tid * 2;
    float acc[8][2];
#pragma unroll
    for (int r = 0; r < 8; ++r) { acc[r][0] = 0.f; acc[r][1] = 0.f; }
    for (int k = 0; k < 1024; k += 4) {
        float2 w0 = *(const float2*)&Wk[(size_t)(k + 0) * 512 + c];
        float2 w1 = *(const float2*)&Wk[(size_t)(k + 1) * 512 + c];
        float2 w2 = *(const float2*)&Wk[(size_t)(k + 2) * 512 + c];
        float2 w3 = *(const float2*)&Wk[(size_t)(k + 3) * 512 + c];
#pragma unroll
        for (int r = 0; r < 8; ++r) {
            float4 x4 = *(const float4*)&sx[r][k];
            acc[r][0] += x4.x * w0.x + x4.y * w1.x + x4.z * w2.x + x4.w * w3.x;
            acc[r][1] += x4.x * w0.y + x4.y * w1.y + x4.z * w2.y + x4.w * w3.y;
        }
    }
#pragma unroll
    for (int r = 0; r < 8; ++r)
        *(float2*)&kp[(size_t)(g0 + r) * 512 + c] = make_float2(acc[r][0], acc[r][1]);
}

// q_all[tn][c] = battn[c] + hD_all[tn] . Wd[:,c]; 8 rows/block, grid (120,2)
__global__ __launch_bounds__(256) void qall_kernel(const float* __restrict__ hall,
                                                   const float* __restrict__ Wd,
                                                   const float* __restrict__ battn,
                                                   float* __restrict__ qall) {
    __shared__ float sx[8][512];
    int tid = threadIdx.x;
    int g0 = blockIdx.x * 8;
    for (int i = tid; i < 8 * 512; i += 256)
        sx[i >> 9][i & 511] = hall[(size_t)(g0 + (i >> 9)) * 512 + (i & 511)];
    __syncthreads();
    int c = blockIdx.y * 256 + tid;
    float b = battn[c];
    float acc[8];
#pragma unroll
    for (int r = 0; r < 8; ++r) acc[r] = b;
    for (int k = 0; k < 512; k += 4) {
        float w0 = Wd[(size_t)(k + 0) * 512 + c];
        float w1 = Wd[(size_t)(k + 1) * 512 + c];
        float w2 = Wd[(size_t)(k + 2) * 512 + c];
        float w3 = Wd[(size_t)(k + 3) * 512 + c];
#pragma unroll
        for (int r = 0; r < 8; ++r) {
            float4 x4 = *(const float4*)&sx[r][k];
            acc[r] += x4.x * w0 + x4.y * w1 + x4.z * w2 + x4.w * w3;
        }
    }
#pragma unroll
    for (int r = 0; r < 8; ++r) qall[(size_t)(g0 + r) * 512 + c] = acc[r];
}

// e_all[(tn)*SRC+s] = v . tanh(kp[n,s,:] + q_all[tn]) + mask ; 4 rows/block
__global__ __launch_bounds__(256) void escoreall_kernel(const float* __restrict__ kp,
                                                        const float* __restrict__ qall,
                                                        const float* __restrict__ vvec,
                                                        const float* __restrict__ mask,
                                                        float* __restrict__ e) {
    __shared__ float sq[512];
    int tid = threadIdx.x;
    int row0 = blockIdx.x * 4;
    int tn = row0 / SRC;
    int n = tn % NB;
    sq[tid] = qall[(size_t)tn * 512 + tid];
    sq[256 + tid] = qall[(size_t)tn * 512 + 256 + tid];
    __syncthreads();
    int w = tid >> 6, lane = tid & 63;
    int row = row0 + w;
    int s = row % SRC;
    const float* kpr = kp + (size_t)(n * SRC + s) * 512;
    float acc = 0.f;
#pragma unroll
    for (int i = 0; i < 8; ++i) {
        int d = lane + i * 64;
        acc += vvec[d] * tanhf(kpr[d] + sq[d]);
    }
    for (int off = 32; off; off >>= 1) acc += __shfl_down(acc, off, 64);
    if (lane == 0) e[row] = acc + (1.f - mask[n * SRC + s]) * (-1e10f);
}

// softmax over SRC per row, in place. block per row.
__global__ __launch_bounds__(256) void softmaxS_kernel(float* __restrict__ e) {
    __shared__ float red[256];
    int n = blockIdx.x, tid = threadIdx.x;
    float* row = e + (size_t)n * SRC;
    float m = -3.4e38f;
    for (int s = tid; s < SRC; s += 256) m = fmaxf(m, row[s]);
    red[tid] = m; __syncthreads();
    for (int off = 128; off; off >>= 1) { if (tid < off) red[tid] = fmaxf(red[tid], red[tid + off]); __syncthreads(); }
    m = red[0]; __syncthreads();
    float sum = 0.f;
    for (int s = tid; s < SRC; s += 256) sum += expf(row[s] - m);
    red[tid] = sum; __syncthreads();
    for (int off = 128; off; off >>= 1) { if (tid < off) red[tid] += red[tid + off]; __syncthreads(); }
    float inv = 1.f / red[0]; __syncthreads();
    for (int s = tid; s < SRC; s += 256) row[s] = expf(row[s] - m) * inv;
}

// ctx_all[(t*NB+n)*1024+d] = sum_s attn[(t*NB+n)*SRC+s]*enc[n,s,d]; grid (32,4)
__global__ __launch_bounds__(256) void ctxall_kernel(const float* __restrict__ attn,
                                                     const float* __restrict__ enc,
                                                     float* __restrict__ ctxall) {
    __shared__ float sa[TDD * SRC];   // 48 KB
    int n = blockIdx.x, tid = threadIdx.x;
    for (int i = tid; i < TDD * SRC; i += 256) {
        int t = i / SRC, s = i - t * SRC;
        sa[i] = attn[(size_t)(t * NB + n) * SRC + s];
    }
    __syncthreads();
    int d = blockIdx.y * 256 + tid;
    const float* er = enc + (size_t)n * SRC * 1024 + d;
    float acc[TDD];
#pragma unroll
    for (int t = 0; t < TDD; ++t) acc[t] = 0.f;
    for (int s = 0; s < SRC; s += 4) {
        float e0 = er[(size_t)(s + 0) * 1024];
        float e1 = er[(size_t)(s + 1) * 1024];
        float e2 = er[(size_t)(s + 2) * 1024];
        float e3 = er[(size_t)(s + 3) * 1024];
#pragma unroll
        for (int t = 0; t < TDD; ++t) {
            float4 a4 = *(const float4*)&sa[t * SRC + s];
            acc[t] += a4.x * e0 + a4.y * e1 + a4.z * e2 + a4.w * e3;
        }
    }
#pragma unroll
    for (int t = 0; t < TDD; ++t) ctxall[(size_t)(t * NB + n) * 1024 + d] = acc[t];
}

// pgen_all[tn] = sigmoid([xi, ctx, h] . Wp + bp); block per tn, grid 960
__global__ __launch_bounds__(256) void pgenall_kernel(const int* __restrict__ trg_ids,
                                                      const float* __restrict__ embed,
                                                      const float* __restrict__ ctxall,
                                                      const float* __restrict__ hall,
                                                      const float* __restrict__ Wp,
                                                      const float* __restrict__ bp,
                                                      float* __restrict__ pgenall) {
    __shared__ float red[256];
    int tn = blockIdx.x, tid = threadIdx.x;
    int t = tn / NB, n = tn % NB;
    int tok = trg_ids[n * TDD + t];
    float acc = 0.f;
    for (int i = tid; i < 1792; i += 256) {
        float val;
        if (i < 256) val = embed[(size_t)tok * EMB + i];
        else if (i < 1280) val = ctxall[(size_t)tn * 1024 + (i - 256)];
        else val = hall[(size_t)tn * 512 + (i - 1280)];
        acc += val * Wp[i];
    }
    red[tid] = acc; __syncthreads();
    for (int off = 128; off; off >>= 1) { if (tid < off) red[tid] += red[tid + off]; __syncthreads(); }
    if (tid == 0) pgenall[tn] = 1.f / (1.f + expf(-(red[0] + bp[0])));
}

// hid1_all[tn][c] = b1[c] + [h,ctx] . W1[:,c]; 8 rows/block, grid (120,2)
__global__ __launch_bounds__(256) void hid1all_kernel(const float* __restrict__ hall,
                                                      const float* __restrict__ ctxall,
                                                      const float* __restrict__ W1,
                                                      const float* __restrict__ b1,
                                                      float* __restrict__ hid1all) {
    __shared__ float sc[8][1536];   // 48 KB
    int tid = threadIdx.x;
    int g0 = blockIdx.x * 8;
    for (int i = tid; i < 8 * 512; i += 256)
        sc[i >> 9][i & 511] = hall[(size_t)(g0 + (i >> 9)) * 512 + (i & 511)];
    for (int i = tid; i < 8 * 1024; i += 256)
        sc[i >> 10][512 + (i & 1023)] = ctxall[(size_t)(g0 + (i >> 10)) * 1024 + (i & 1023)];
    __syncthreads();
    int c = blockIdx.y * 256 + tid;
    float acc[8];
    float b = b1[c];
#pragma unroll
    for (int r = 0; r < 8; ++r) acc[r] = b;
    for (int k = 0; k < 1536; k += 4) {
        float w0 = W1[(size_t)(k + 0) * 512 + c];
        float w1 = W1[(size_t)(k + 1) * 512 + c];
        float w2 = W1[(size_t)(k + 2) * 512 + c];
        float w3 = W1[(size_t)(k + 3) * 512 + c];
#pragma unroll
        for (int r = 0; r < 8; ++r) {
            float4 x4 = *(const float4*)&sc[r][k];
            acc[r] += x4.x * w0 + x4.y * w1 + x4.z * w2 + x4.w * w3;
        }
    }
#pragma unroll
    for (int r = 0; r < 8; ++r) hid1all[(size_t)(g0 + r) * 512 + c] = acc[r];
}

// logits: rows=16, J=4 j/thread, float4 W2 loads. grid (49, 60), 256 thr.
__global__ __launch_bounds__(256) void logitsall_kernel(const float* __restrict__ hid1,
                                                        const float* __restrict__ W2,
                                                        const float* __restrict__ b2,
                                                        float* __restrict__ logits) {
    __shared__ float sh[16][512];   // 32 KB
    int tid = threadIdx.x;
    int r0 = blockIdx.y * 16;
    for (int i = tid; i < 16 * 512; i += 256) sh[i >> 9][i & 511] = hid1[(size_t)r0 * 512 + i];
    __syncthreads();
    int j = blockIdx.x * 1024 + tid * 4;
    if (j >= VSZ) return;
    float acc[16][4];
#pragma unroll
    for (int r = 0; r < 16; ++r) { acc[r][0]=0.f; acc[r][1]=0.f; acc[r][2]=0.f; acc[r][3]=0.f; }
    for (int k = 0; k < 512; k += 4) {
        float4 w0 = *(const float4*)&W2[(size_t)(k + 0) * VSZ + j];
        float4 w1 = *(const float4*)&W2[(size_t)(k + 1) * VSZ + j];
        float4 w2 = *(const float4*)&W2[(size_t)(k + 2) * VSZ + j];
        float4 w3 = *(const float4*)&W2[(size_t)(k + 3) * VSZ + j];
#pragma unroll
        for (int r = 0; r < 16; ++r) {
            float4 h4 = *(const float4*)&sh[r][k];
            acc[r][0] += h4.x * w0.x + h4.y * w1.x + h4.z * w2.x + h4.w * w3.x;
            acc[r][1] += h4.x * w0.y + h4.y * w1.y + h4.z * w2.y + h4.w * w3.y;
            acc[r][2] += h4.x * w0.z + h4.y * w1.z + h4.z * w2.z + h4.w * w3.z;
            acc[r][3] += h4.x * w0.w + h4.y * w1.w + h4.z * w2.w + h4.w * w3.w;
        }
    }
    float4 bb = *(const float4*)&b2[j];
#pragma unroll
    for (int r = 0; r < 16; ++r) {
        float4 o;
        o.x = acc[r][0] + bb.x; o.y = acc[r][1] + bb.y;
        o.z = acc[r][2] + bb.z; o.w = acc[r][3] + bb.w;
        *(float4*)&logits[(size_t)(r0 + r) * VSZ + j] = o;
    }
}

// softmax over V, scale by p_gen, write out row; block per tn
__global__ __launch_bounds__(1024) void outall_kernel(const float* __restrict__ logits,
                                                      const float* __restrict__ pgenall,
                                                      float* __restrict__ out) {
    __shared__ float red[1024];
    int tn = blockIdx.x, tid = threadIdx.x;
    int t = tn / NB, n = tn % NB;
    const float* lrow = logits + (size_t)tn * VSZ;
    float m = -3.4e38f;
    for (int jj = tid; jj < VSZ; jj += 1024) m = fmaxf(m, lrow[jj]);
    red[tid] = m; __syncthreads();
    for (int off = 512; off; off >>= 1) { if (tid < off) red[tid] = fmaxf(red[tid], red[tid + off]); __syncthreads(); }
    m = red[0]; __syncthreads();
    float sum = 0.f;
    for (int jj = tid; jj < VSZ; jj += 1024) sum += expf(lrow[jj] - m);
    red[tid] = sum; __syncthreads();
    for (int off = 512; off; off >>= 1) { if (tid < off) red[tid] += red[tid + off]; __syncthreads(); }
    float inv = pgenall[tn] / red[0];
    float* orow = out + (size_t)(n * TDD + t) * VE;
    for (int jj = tid; jj < VE; jj += 1024) orow[jj] = (jj < VSZ) ? expf(lrow[jj] - m) * inv : 0.f;
}

// out[n, t, ptr[n,s]] += (1-p_gen[tn]) * attn[tn,s] for all t,n,s
__global__ __launch_bounds__(256) void scatterall_kernel(const int* __restrict__ ptr,
                                                         const float* __restrict__ attn,
                                                         const float* __restrict__ pgenall,
                                                         float* __restrict__ out) {
    int f = blockIdx.x * 256 + threadIdx.x;
    if (f >= TDD * NB * SRC) return;
    int tn = f / SRC;
    int s = f - tn * SRC;
    int t = tn / NB, n = tn % NB;
    float w = (1.f - pgenall[tn]) * attn[f];
    atomicAdd(&out[(size_t)(n * TDD + t) * VE + ptr[n * SRC + s]], w);
}

extern "C" void kernel_launch(void* const* d_in, const int* in_sizes, int n_in,
                              void* d_out, int out_size, void* d_ws, size_t ws_size,
                              hipStream_t stream) {
    const int*   src_ids  = (const int*)d_in[0];
    const float* src_mask = (const float*)d_in[1];
    const int*   trg_ids  = (const int*)d_in[2];
    const int*   ptr_idx  = (const int*)d_in[3];
    const float* embed    = (const float*)d_in[4];
    const float* Wih_f = (const float*)d_in[5];
    const float* Whh_f = (const float*)d_in[6];
    const float* bih_f = (const float*)d_in[7];
    const float* bhh_f = (const float*)d_in[8];
    const float* Wih_b = (const float*)d_in[9];
    const float* Whh_b = (const float*)d_in[10];
    const float* bih_b = (const float*)d_in[11];
    const float* bhh_b = (const float*)d_in[12];
    const float* Wih_d = (const float*)d_in[13];
    const float* Whh_d = (const float*)d_in[14];
    const float* bih_d = (const float*)d_in[15];
    const float* bhh_d = (const float*)d_in[16];
    const float* Wk    = (const float*)d_in[17];
    const float* Wd    = (const float*)d_in[18];
    const float* battn = (const float*)d_in[19];
    const float* vvec  = (const float*)d_in[20];
    const float* W1    = (const float*)d_in[21];
    const float* b1    = (const float*)d_in[22];
    const float* W2    = (const float*)d_in[23];
    const float* b2    = (const float*)d_in[24];
    const float* Wp    = (const float*)d_in[25];
    const float* bp    = (const float*)d_in[26];
    float* out = (float*)d_out;

    float* w = (float*)d_ws;
    float* WihTf = w; w += 256 * G3;
    float* WihTb = w; w += 256 * G3;
    float* WihTd = w; w += 256 * G3;
    float* giF = w; w += (size_t)SRC * NB * G3;   // dead after fused_scan
    float* giB = w; w += (size_t)SRC * NB * G3;   // dead after fused_scan
    float* giD = w; w += (size_t)SRC * NB * G3;   // oversize alloc, only TDD used
    float* enc = w; w += (size_t)NB * SRC * 1024;
    float* kp  = w; w += (size_t)NB * SRC * 512;
    float* hF0 = w; w += NB * HE;
    float* hF1 = w; w += NB * HE;
    float* hB0 = w; w += NB * HE;
    float* hB1 = w; w += NB * HE;
    float* h0d = w; w += NB * HD;
    float* hDs = w; w += (size_t)TDD * NB * HD;     // bypass shadow
    float* hD_all = w; w += (size_t)TDD * NB * HD;  // normal copy for downstream
    float* q_all  = w; w += (size_t)TDD * NB * 512;
    float* e_all  = w; w += (size_t)TDD * NB * SRC;
    float* ctx_all = w; w += (size_t)TDD * NB * 1024;
    float* hid1_all = w; w += (size_t)TDD * NB * 512;
    float* pgen_all = w; w += 1024;
    unsigned int* flags = (unsigned int*)w; w += (2 * SRC + TDD) * 128;
    // logits_all (960*50000 = 48M floats) aliases giF..enc-prefix (dead by then)
    float* logits_all = giF;

    // ---- weight transposes (WihT x3 for gi) ----
    transpose_kernel<<<(G3 * 256 + 255) / 256, 256, 0, stream>>>(Wih_f, WihTf, G3, 256);
    transpose_kernel<<<(G3 * 256 + 255) / 256, 256, 0, stream>>>(Wih_b, WihTb, G3, 256);
    transpose_kernel<<<(G3 * 256 + 255) / 256, 256, 0, stream>>>(Wih_d, WihTd, G3, 256);

    // ---- input-gate precompute ----
    gi_kernel<<<dim3(SRC * NB / 16, 6), 256, 0, stream>>>(src_ids, embed, WihTf, bih_f, giF, SRC);
    gi_kernel<<<dim3(SRC * NB / 16, 6), 256, 0, stream>>>(src_ids, embed, WihTb, bih_b, giB, SRC);
    gi_kernel<<<dim3(TDD * NB / 16, 6), 256, 0, stream>>>(trg_ids, embed, WihTd, bih_d, giD, TDD);

    hipMemsetAsync(hF0, 0, NB * HE * sizeof(float), stream);
    hipMemsetAsync(hB0, 0, NB * HE * sizeof(float), stream);
    hipMemsetAsync(h0d, 0, NB * HD * sizeof(float), stream);
    hipMemsetAsync(flags, 0, (2 * SRC + TDD) * 128 * sizeof(unsigned int), stream);

    // ---- fused persistent scan: fwd + bwd + dec, barrier latency hidden ----
    fused_scan_kernel<<<FSCAN_NBLK, 512, 0, stream>>>(
        giF, giB, giD, Whh_f, Whh_b, Whh_d, bhh_f, bhh_b, bhh_d,
        hF0, hF1, hB0, hB1, h0d, hDs, hD_all, enc, flags);

    keyproj_kernel<<<NB * SRC / 8, 256, 0, stream>>>(enc, Wk, kp);

    // ---- fully batched decoder head over all 30 steps ----
    qall_kernel<<<dim3(TDD * NB / 8, 2), 256, 0, stream>>>(hD_all, Wd, battn, q_all);
    escoreall_kernel<<<TDD * NB * SRC / 4, 256, 0, stream>>>(kp, q_all, vvec, src_mask, e_all);
    softmaxS_kernel<<<TDD * NB, 256, 0, stream>>>(e_all);
    ctxall_kernel<<<dim3(NB, 4), 256, 0, stream>>>(e_all, enc, ctx_all);
    pgenall_kernel<<<TDD * NB, 256, 0, stream>>>(trg_ids, embed, ctx_all, hD_all, Wp, bp, pgen_all);
    hid1all_kernel<<<dim3(TDD * NB / 8, 2), 256, 0, stream>>>(hD_all, ctx_all, W1, b1, hid1_all);
    logitsall_kernel<<<dim3((VSZ + 1023) / 1024, TDD * NB / 16), 256, 0, stream>>>(hid1_all, W2, b2, logits_all);
    outall_kernel<<<TDD * NB, 1024, 0, stream>>>(logits_all, pgen_all, out);
    scatterall_kernel<<<(TDD * NB * SRC + 255) / 256, 256, 0, stream>>>(ptr_idx, e_all, pgen_all, out);
}

// Round 6
// 13027.058 us; speedup vs baseline: 1.2642x; 1.2642x over previous
//
#include <hip/hip_runtime.h>
#include <math.h>

#define VSZ 50000
#define OOVN 50
#define VE 50050
#define EMB 256
#define HE 512
#define HD 512
#define NB 32
#define SRC 400
#define TDD 30
#define G3 1536   // 3*HE = 3*HD

__device__ __forceinline__ float sigmf(float x) { return 1.f / (1.f + expf(-x)); }

// out[c*rows + r] = in[r*cols + c]
__global__ __launch_bounds__(256) void transpose_kernel(const float* __restrict__ in,
                                                        float* __restrict__ out,
                                                        int rows, int cols) {
    int idx = blockIdx.x * 256 + threadIdx.x;
    if (idx >= rows * cols) return;
    int r = idx / cols, c = idx % cols;
    out[c * rows + r] = in[idx];
}

// gi[(s*NB+n)*G3 + c] = bih[c] + sum_e embed[ids[n*steps+s]][e] * WihT[e*G3+c]
__global__ __launch_bounds__(256) void gi_kernel(const int* __restrict__ ids,
                                                 const float* __restrict__ embed,
                                                 const float* __restrict__ WihT,
                                                 const float* __restrict__ bih,
                                                 float* __restrict__ gi, int steps) {
    __shared__ float sx[16][EMB];
    __shared__ int stok[16];
    int tid = threadIdx.x;
    int g0 = blockIdx.x * 16;
    if (tid < 16) {
        int row = g0 + tid;
        int s = row / NB, n = row % NB;
        stok[tid] = ids[n * steps + s];
    }
    __syncthreads();
    for (int r = 0; r < 16; ++r) sx[r][tid] = embed[(size_t)stok[r] * EMB + tid];
    __syncthreads();
    int c = blockIdx.y * 256 + tid;
    float b = bih[c];
    float acc[16];
#pragma unroll
    for (int r = 0; r < 16; ++r) acc[r] = b;
    for (int e = 0; e < EMB; e += 4) {
        float w0 = WihT[(size_t)(e + 0) * G3 + c];
        float w1 = WihT[(size_t)(e + 1) * G3 + c];
        float w2 = WihT[(size_t)(e + 2) * G3 + c];
        float w3 = WihT[(size_t)(e + 3) * G3 + c];
#pragma unroll
        for (int r = 0; r < 16; ++r) {
            float4 x4 = *(const float4*)&sx[r][e];
            acc[r] += x4.x * w0 + x4.y * w1 + x4.z * w2 + x4.w * w3;
        }
    }
#pragma unroll
    for (int r = 0; r < 16; ++r) gi[(size_t)(g0 + r) * G3 + c] = acc[r];
}

// ---------------- persistent encoder scan, (jc x nc) partition ----------------
// grid (128, 2): y = dir; x: jc = bid>>2 (16 j-cols), nc = bid&3 (8 n-rows).
// 512 thr: jl = tid&15, kh = (tid>>4)&3 (k-chunk of 128), ng = tid>>6 (1 n each).
// Block stages ONLY its 8 h-rows (16 KB) via bypass loads; weights stream from
// L1 (same addresses every step). Partial barrier: poll the 32 same-nc flags.
__global__ __launch_bounds__(512) void enc_scan_kernel(
    const float* __restrict__ giF, const float* __restrict__ giB,
    const float* __restrict__ WhhF, const float* __restrict__ WhhB,
    const float* __restrict__ bhhF, const float* __restrict__ bhhB,
    float* __restrict__ hF0, float* __restrict__ hF1,
    float* __restrict__ hB0, float* __restrict__ hB1,
    float* __restrict__ enc, unsigned int* __restrict__ flags) {
    const int z = blockIdx.y;
    const int bid = blockIdx.x;
    const int jc = bid >> 2, nc = bid & 3;
    const int j0 = jc * 16, n0 = nc * 8;
    const float* gi  = z ? giB : giF;
    const float* Whh = z ? WhhB : WhhF;
    const float* bhh = z ? bhhB : bhhF;
    float* hbuf[2];
    hbuf[0] = z ? hB0 : hF0;
    hbuf[1] = z ? hB1 : hF1;
    unsigned int* fl = flags + (size_t)z * SRC * 128;

    __shared__ float hlds[8 * 528];   // [ng][kh*132 + i]  16.9 KB

    const int tid = threadIdx.x;
    const int jl = tid & 15;
    const int kh = (tid >> 4) & 3;
    const int ng = tid >> 6;
    const int j = j0 + jl;
    const int n = n0 + ng;

    const float bR = bhh[j], bZ = bhh[512 + j], bN = bhh[1024 + j];
    const float* wR = Whh + (size_t)(0 * 512 + j) * 512 + kh * 128;
    const float* wZ = Whh + (size_t)(1 * 512 + j) * 512 + kh * 128;
    const float* wN = Whh + (size_t)(2 * 512 + j) * 512 + kh * 128;

    for (int t = 0; t < SRC; ++t) {
        const int s = z ? (SRC - 1 - t) : t;
        const float* hin = hbuf[t & 1];
        float* hout = hbuf[(t + 1) & 1];

        // gi prefetch: one aligned 64B line per (n, gate) across jl lanes
        float g0v = 0.f, g1v = 0.f, g2v = 0.f;
        if (kh == 0) {
            const float* gir = gi + (size_t)(s * NB + n) * G3 + j;
            g0v = gir[0]; g1v = gir[512]; g2v = gir[1024];
        }

        // stage ONLY this block's 8 h-rows (16 KB) via 8B bypass loads
        const unsigned long long* hin8 = (const unsigned long long*)(hin + n0 * 512);
        for (int idx = tid; idx < 8 * 256; idx += 512) {
            unsigned long long uv = __hip_atomic_load(&hin8[idx], __ATOMIC_RELAXED,
                                                      __HIP_MEMORY_SCOPE_AGENT);
            union { unsigned long long u; float f[2]; } cv; cv.u = uv;
            int nn = idx >> 8, kk = (idx & 255) << 1;
            int off = nn * 528 + (kk >> 7) * 132 + (kk & 127);
            hlds[off] = cv.f[0];
            hlds[off + 1] = cv.f[1];
        }
        __syncthreads();

        float aR = 0.f, aZ = 0.f, aN = 0.f;
        const float* hrow = &hlds[ng * 528 + kh * 132];
#pragma unroll 8
        for (int i = 0; i < 128; i += 4) {
            float4 h4 = *(const float4*)&hrow[i];
            float4 wr = *(const float4*)&wR[i];
            float4 wz = *(const float4*)&wZ[i];
            float4 wn = *(const float4*)&wN[i];
            aR += h4.x*wr.x + h4.y*wr.y + h4.z*wr.z + h4.w*wr.w;
            aZ += h4.x*wz.x + h4.y*wz.y + h4.z*wz.z + h4.w*wz.w;
            aN += h4.x*wn.x + h4.y*wn.y + h4.z*wn.z + h4.w*wn.w;
        }
        // reduce over kh (tid bits 4-5, within the 64-lane wave)
        aR += __shfl_xor(aR, 16); aR += __shfl_xor(aR, 32);
        aZ += __shfl_xor(aZ, 16); aZ += __shfl_xor(aZ, 32);
        aN += __shfl_xor(aN, 16); aN += __shfl_xor(aN, 32);

        if (kh == 0) {
            float rr  = sigmf(g0v + bR + aR);
            float zz  = sigmf(g1v + bZ + aZ);
            float nn2 = tanhf(g2v + bN + rr * aN);
            float hp  = hlds[ng * 528 + (j >> 7) * 132 + (j & 127)];
            float hnew = (1.f - zz) * nn2 + zz * hp;
            __hip_atomic_store(&hout[n * 512 + j], hnew, __ATOMIC_RELAXED,
                               __HIP_MEMORY_SCOPE_AGENT);
            enc[(size_t)(n * SRC + s) * 1024 + z * 512 + j] = hnew;
        }
        __syncthreads();   // per-wave store drain before flag
        if (tid == 0)
            __hip_atomic_store(&fl[t * 128 + nc * 32 + jc], 1u, __ATOMIC_RELAXED,
                               __HIP_MEMORY_SCOPE_AGENT);
        if (t != SRC - 1) {
            // partial barrier: only the 32 same-nc producers matter
            if (tid < 64) {
                const unsigned int* ft = fl + t * 128 + nc * 32;
                while (!__all(__hip_atomic_load(&ft[tid & 31], __ATOMIC_RELAXED,
                                                __HIP_MEMORY_SCOPE_AGENT) != 0u))
                    __builtin_amdgcn_s_sleep(1);
            }
            __syncthreads();
        }
    }
}

// ---------------- persistent decoder recurrence, same partition (128 blocks) ----
__global__ __launch_bounds__(512) void dec_scan_kernel(
    const float* __restrict__ gi, const float* __restrict__ Whh,
    const float* __restrict__ bhh, const float* __restrict__ h0,
    float* __restrict__ hDs, float* __restrict__ hD_all,
    unsigned int* __restrict__ flags) {
    const int bid = blockIdx.x;
    const int jc = bid >> 2, nc = bid & 3;
    const int j0 = jc * 16, n0 = nc * 8;
    __shared__ float hlds[8 * 528];
    const int tid = threadIdx.x;
    const int jl = tid & 15;
    const int kh = (tid >> 4) & 3;
    const int ng = tid >> 6;
    const int j = j0 + jl;
    const int n = n0 + ng;

    const float bR = bhh[j], bZ = bhh[512 + j], bN = bhh[1024 + j];
    const float* wR = Whh + (size_t)(0 * 512 + j) * 512 + kh * 128;
    const float* wZ = Whh + (size_t)(1 * 512 + j) * 512 + kh * 128;
    const float* wN = Whh + (size_t)(2 * 512 + j) * 512 + kh * 128;

    for (int t = 0; t < TDD; ++t) {
        const float* hin = t ? (hDs + (size_t)(t - 1) * NB * 512) : h0;
        float* hout = hDs + (size_t)t * NB * 512;

        float g0v = 0.f, g1v = 0.f, g2v = 0.f;
        if (kh == 0) {
            const float* gir = gi + (size_t)(t * NB + n) * G3 + j;
            g0v = gir[0]; g1v = gir[512]; g2v = gir[1024];
        }

        const unsigned long long* hin8 = (const unsigned long long*)(hin + n0 * 512);
        for (int idx = tid; idx < 8 * 256; idx += 512) {
            unsigned long long uv = __hip_atomic_load(&hin8[idx], __ATOMIC_RELAXED,
                                                      __HIP_MEMORY_SCOPE_AGENT);
            union { unsigned long long u; float f[2]; } cv; cv.u = uv;
            int nn = idx >> 8, kk = (idx & 255) << 1;
            int off = nn * 528 + (kk >> 7) * 132 + (kk & 127);
            hlds[off] = cv.f[0];
            hlds[off + 1] = cv.f[1];
        }
        __syncthreads();

        float aR = 0.f, aZ = 0.f, aN = 0.f;
        const float* hrow = &hlds[ng * 528 + kh * 132];
#pragma unroll 8
        for (int i = 0; i < 128; i += 4) {
            float4 h4 = *(const float4*)&hrow[i];
            float4 wr = *(const float4*)&wR[i];
            float4 wz = *(const float4*)&wZ[i];
            float4 wn = *(const float4*)&wN[i];
            aR += h4.x*wr.x + h4.y*wr.y + h4.z*wr.z + h4.w*wr.w;
            aZ += h4.x*wz.x + h4.y*wz.y + h4.z*wz.z + h4.w*wz.w;
            aN += h4.x*wn.x + h4.y*wn.y + h4.z*wn.z + h4.w*wn.w;
        }
        aR += __shfl_xor(aR, 16); aR += __shfl_xor(aR, 32);
        aZ += __shfl_xor(aZ, 16); aZ += __shfl_xor(aZ, 32);
        aN += __shfl_xor(aN, 16); aN += __shfl_xor(aN, 32);

        if (kh == 0) {
            float rr  = sigmf(g0v + bR + aR);
            float zz  = sigmf(g1v + bZ + aZ);
            float nn2 = tanhf(g2v + bN + rr * aN);
            float hp  = hlds[ng * 528 + (j >> 7) * 132 + (j & 127)];
            float hnew = (1.f - zz) * nn2 + zz * hp;
            __hip_atomic_store(&hout[n * 512 + j], hnew, __ATOMIC_RELAXED,
                               __HIP_MEMORY_SCOPE_AGENT);
            hD_all[(size_t)t * NB * 512 + n * 512 + j] = hnew;   // normal store for downstream
        }
        __syncthreads();
        if (tid == 0)
            __hip_atomic_store(&flags[t * 128 + nc * 32 + jc], 1u, __ATOMIC_RELAXED,
                               __HIP_MEMORY_SCOPE_AGENT);
        if (t != TDD - 1) {
            if (tid < 64) {
                const unsigned int* ft = flags + t * 128 + nc * 32;
                while (!__all(__hip_atomic_load(&ft[tid & 31], __ATOMIC_RELAXED,
                                                __HIP_MEMORY_SCOPE_AGENT) != 0u))
                    __builtin_amdgcn_s_sleep(1);
            }
            __syncthreads();
        }
    }
}

// key_proj J=2: kp[row*512 + c] = sum_k enc[row][k]*Wk[k*512+c]; 8 rows/block, grid 1600
__global__ __launch_bounds__(256) void keyproj_kernel(const float* __restrict__ enc,
                                                      const float* __restrict__ Wk,
                                                      float* __restrict__ kp) {
    __shared__ float sx[8][1024];
    int tid = threadIdx.x;
    int g0 = blockIdx.x * 8;
    for (int i = tid; i < 8 * 1024; i += 256)
        sx[i >> 10][i & 1023] = enc[(size_t)(g0 + (i >> 10)) * 1024 + (i & 1023)];
    __syncthreads();
    int c = tid * 2;
    float acc[8][2];
#pragma unroll
    for (int r = 0; r < 8; ++r) { acc[r][0] = 0.f; acc[r][1] = 0.f; }
    for (int k = 0; k < 1024; k += 4) {
        float2 w0 = *(const float2*)&Wk[(size_t)(k + 0) * 512 + c];
        float2 w1 = *(const float2*)&Wk[(size_t)(k + 1) * 512 + c];
        float2 w2 = *(const float2*)&Wk[(size_t)(k + 2) * 512 + c];
        float2 w3 = *(const float2*)&Wk[(size_t)(k + 3) * 512 + c];
#pragma unroll
        for (int r = 0; r < 8; ++r) {
            float4 x4 = *(const float4*)&sx[r][k];
            acc[r][0] += x4.x * w0.x + x4.y * w1.x + x4.z * w2.x + x4.w * w3.x;
            acc[r][1] += x4.x * w0.y + x4.y * w1.y + x4.z * w2.y + x4.w * w3.y;
        }
    }
#pragma unroll
    for (int r = 0; r < 8; ++r)
        *(float2*)&kp[(size_t)(g0 + r) * 512 + c] = make_float2(acc[r][0], acc[r][1]);
}

// q_all[tn][c] = battn[c] + hD_all[tn] . Wd[:,c]; 8 rows/block, grid (120,2)
__global__ __launch_bounds__(256) void qall_kernel(const float* __restrict__ hall,
                                                   const float* __restrict__ Wd,
                                                   const float* __restrict__ battn,
                                                   float* __restrict__ qall) {
    __shared__ float sx[8][512];
    int tid = threadIdx.x;
    int g0 = blockIdx.x * 8;
    for (int i = tid; i < 8 * 512; i += 256)
        sx[i >> 9][i & 511] = hall[(size_t)(g0 + (i >> 9)) * 512 + (i & 511)];
    __syncthreads();
    int c = blockIdx.y * 256 + tid;
    float b = battn[c];
    float acc[8];
#pragma unroll
    for (int r = 0; r < 8; ++r) acc[r] = b;
    for (int k = 0; k < 512; k += 4) {
        float w0 = Wd[(size_t)(k + 0) * 512 + c];
        float w1 = Wd[(size_t)(k + 1) * 512 + c];
        float w2 = Wd[(size_t)(k + 2) * 512 + c];
        float w3 = Wd[(size_t)(k + 3) * 512 + c];
#pragma unroll
        for (int r = 0; r < 8; ++r) {
            float4 x4 = *(const float4*)&sx[r][k];
            acc[r] += x4.x * w0 + x4.y * w1 + x4.z * w2 + x4.w * w3;
        }
    }
#pragma unroll
    for (int r = 0; r < 8; ++r) qall[(size_t)(g0 + r) * 512 + c] = acc[r];
}

// e_all[(tn)*SRC+s] = v . tanh(kp[n,s,:] + q_all[tn]) + mask ; 4 rows/block
__global__ __launch_bounds__(256) void escoreall_kernel(const float* __restrict__ kp,
                                                        const float* __restrict__ qall,
                                                        const float* __restrict__ vvec,
                                                        const float* __restrict__ mask,
                                                        float* __restrict__ e) {
    __shared__ float sq[512];
    int tid = threadIdx.x;
    int row0 = blockIdx.x * 4;
    int tn = row0 / SRC;
    int n = tn % NB;
    sq[tid] = qall[(size_t)tn * 512 + tid];
    sq[256 + tid] = qall[(size_t)tn * 512 + 256 + tid];
    __syncthreads();
    int w = tid >> 6, lane = tid & 63;
    int row = row0 + w;
    int s = row % SRC;
    const float* kpr = kp + (size_t)(n * SRC + s) * 512;
    float acc = 0.f;
#pragma unroll
    for (int i = 0; i < 8; ++i) {
        int d = lane + i * 64;
        acc += vvec[d] * tanhf(kpr[d] + sq[d]);
    }
    for (int off = 32; off; off >>= 1) acc += __shfl_down(acc, off, 64);
    if (lane == 0) e[row] = acc + (1.f - mask[n * SRC + s]) * (-1e10f);
}

// softmax over SRC per row, in place. block per row.
__global__ __launch_bounds__(256) void softmaxS_kernel(float* __restrict__ e) {
    __shared__ float red[256];
    int n = blockIdx.x, tid = threadIdx.x;
    float* row = e + (size_t)n * SRC;
    float m = -3.4e38f;
    for (int s = tid; s < SRC; s += 256) m = fmaxf(m, row[s]);
    red[tid] = m; __syncthreads();
    for (int off = 128; off; off >>= 1) { if (tid < off) red[tid] = fmaxf(red[tid], red[tid + off]); __syncthreads(); }
    m = red[0]; __syncthreads();
    float sum = 0.f;
    for (int s = tid; s < SRC; s += 256) sum += expf(row[s] - m);
    red[tid] = sum; __syncthreads();
    for (int off = 128; off; off >>= 1) { if (tid < off) red[tid] += red[tid + off]; __syncthreads(); }
    float inv = 1.f / red[0]; __syncthreads();
    for (int s = tid; s < SRC; s += 256) row[s] = expf(row[s] - m) * inv;
}

// ctx_all[(t*NB+n)*1024+d] = sum_s attn[(t*NB+n)*SRC+s]*enc[n,s,d]; grid (32,4)
__global__ __launch_bounds__(256) void ctxall_kernel(const float* __restrict__ attn,
                                                     const float* __restrict__ enc,
                                                     float* __restrict__ ctxall) {
    __shared__ float sa[TDD * SRC];   // 48 KB
    int n = blockIdx.x, tid = threadIdx.x;
    for (int i = tid; i < TDD * SRC; i += 256) {
        int t = i / SRC, s = i - t * SRC;
        sa[i] = attn[(size_t)(t * NB + n) * SRC + s];
    }
    __syncthreads();
    int d = blockIdx.y * 256 + tid;
    const float* er = enc + (size_t)n * SRC * 1024 + d;
    float acc[TDD];
#pragma unroll
    for (int t = 0; t < TDD; ++t) acc[t] = 0.f;
    for (int s = 0; s < SRC; s += 4) {
        float e0 = er[(size_t)(s + 0) * 1024];
        float e1 = er[(size_t)(s + 1) * 1024];
        float e2 = er[(size_t)(s + 2) * 1024];
        float e3 = er[(size_t)(s + 3) * 1024];
#pragma unroll
        for (int t = 0; t < TDD; ++t) {
            float4 a4 = *(const float4*)&sa[t * SRC + s];
            acc[t] += a4.x * e0 + a4.y * e1 + a4.z * e2 + a4.w * e3;
        }
    }
#pragma unroll
    for (int t = 0; t < TDD; ++t) ctxall[(size_t)(t * NB + n) * 1024 + d] = acc[t];
}

// pgen_all[tn] = sigmoid([xi, ctx, h] . Wp + bp); block per tn, grid 960
__global__ __launch_bounds__(256) void pgenall_kernel(const int* __restrict__ trg_ids,
                                                      const float* __restrict__ embed,
                                                      const float* __restrict__ ctxall,
                                                      const float* __restrict__ hall,
                                                      const float* __restrict__ Wp,
                                                      const float* __restrict__ bp,
                                                      float* __restrict__ pgenall) {
    __shared__ float red[256];
    int tn = blockIdx.x, tid = threadIdx.x;
    int t = tn / NB, n = tn % NB;
    int tok = trg_ids[n * TDD + t];
    float acc = 0.f;
    for (int i = tid; i < 1792; i += 256) {
        float val;
        if (i < 256) val = embed[(size_t)tok * EMB + i];
        else if (i < 1280) val = ctxall[(size_t)tn * 1024 + (i - 256)];
        else val = hall[(size_t)tn * 512 + (i - 1280)];
        acc += val * Wp[i];
    }
    red[tid] = acc; __syncthreads();
    for (int off = 128; off; off >>= 1) { if (tid < off) red[tid] += red[tid + off]; __syncthreads(); }
    if (tid == 0) pgenall[tn] = 1.f / (1.f + expf(-(red[0] + bp[0])));
}

// hid1_all[tn][c] = b1[c] + [h,ctx] . W1[:,c]; 8 rows/block, grid (120,2)
__global__ __launch_bounds__(256) void hid1all_kernel(const float* __restrict__ hall,
                                                      const float* __restrict__ ctxall,
                                                      const float* __restrict__ W1,
                                                      const float* __restrict__ b1,
                                                      float* __restrict__ hid1all) {
    __shared__ float sc[8][1536];   // 48 KB
    int tid = threadIdx.x;
    int g0 = blockIdx.x * 8;
    for (int i = tid; i < 8 * 512; i += 256)
        sc[i >> 9][i & 511] = hall[(size_t)(g0 + (i >> 9)) * 512 + (i & 511)];
    for (int i = tid; i < 8 * 1024; i += 256)
        sc[i >> 10][512 + (i & 1023)] = ctxall[(size_t)(g0 + (i >> 10)) * 1024 + (i & 1023)];
    __syncthreads();
    int c = blockIdx.y * 256 + tid;
    float acc[8];
    float b = b1[c];
#pragma unroll
    for (int r = 0; r < 8; ++r) acc[r] = b;
    for (int k = 0; k < 1536; k += 4) {
        float w0 = W1[(size_t)(k + 0) * 512 + c];
        float w1 = W1[(size_t)(k + 1) * 512 + c];
        float w2 = W1[(size_t)(k + 2) * 512 + c];
        float w3 = W1[(size_t)(k + 3) * 512 + c];
#pragma unroll
        for (int r = 0; r < 8; ++r) {
            float4 x4 = *(const float4*)&sc[r][k];
            acc[r] += x4.x * w0 + x4.y * w1 + x4.z * w2 + x4.w * w3;
        }
    }
#pragma unroll
    for (int r = 0; r < 8; ++r) hid1all[(size_t)(g0 + r) * 512 + c] = acc[r];
}

// logits: 48 rows/block, J=2 j/thread, 512 thr. grid (49, 20). W2 re-read 20x only.
__global__ __launch_bounds__(512) void logitsall_kernel(const float* __restrict__ hid1,
                                                        const float* __restrict__ W2,
                                                        const float* __restrict__ b2,
                                                        float* __restrict__ logits) {
    __shared__ float sh[48][512];   // 96 KB
    int tid = threadIdx.x;
    int r0 = blockIdx.y * 48;
    for (int i = tid; i < 48 * 512; i += 512) sh[i >> 9][i & 511] = hid1[(size_t)r0 * 512 + i];
    __syncthreads();
    int j = blockIdx.x * 1024 + tid * 2;
    if (j >= VSZ) return;
    float acc[48][2];
#pragma unroll
    for (int r = 0; r < 48; ++r) { acc[r][0] = 0.f; acc[r][1] = 0.f; }
    for (int k = 0; k < 512; k += 2) {
        float2 w0 = *(const float2*)&W2[(size_t)(k + 0) * VSZ + j];
        float2 w1 = *(const float2*)&W2[(size_t)(k + 1) * VSZ + j];
#pragma unroll
        for (int r = 0; r < 48; ++r) {
            float2 h2 = *(const float2*)&sh[r][k];
            acc[r][0] += h2.x * w0.x + h2.y * w1.x;
            acc[r][1] += h2.x * w0.y + h2.y * w1.y;
        }
    }
    float2 bb = *(const float2*)&b2[j];
#pragma unroll
    for (int r = 0; r < 48; ++r) {
        float2 o; o.x = acc[r][0] + bb.x; o.y = acc[r][1] + bb.y;
        *(float2*)&logits[(size_t)(r0 + r) * VSZ + j] = o;
    }
}

// softmax over V, scale by p_gen, write out row; block per tn
__global__ __launch_bounds__(1024) void outall_kernel(const float* __restrict__ logits,
                                                      const float* __restrict__ pgenall,
                                                      float* __restrict__ out) {
    __shared__ float red[1024];
    int tn = blockIdx.x, tid = threadIdx.x;
    int t = tn / NB, n = tn % NB;
    const float* lrow = logits + (size_t)tn * VSZ;
    float m = -3.4e38f;
    for (int jj = tid; jj < VSZ; jj += 1024) m = fmaxf(m, lrow[jj]);
    red[tid] = m; __syncthreads();
    for (int off = 512; off; off >>= 1) { if (tid < off) red[tid] = fmaxf(red[tid], red[tid + off]); __syncthreads(); }
    m = red[0]; __syncthreads();
    float sum = 0.f;
    for (int jj = tid; jj < VSZ; jj += 1024) sum += expf(lrow[jj] - m);
    red[tid] = sum; __syncthreads();
    for (int off = 512; off; off >>= 1) { if (tid < off) red[tid] += red[tid + off]; __syncthreads(); }
    float inv = pgenall[tn] / red[0];
    float* orow = out + (size_t)(n * TDD + t) * VE;
    for (int jj = tid; jj < VE; jj += 1024) orow[jj] = (jj < VSZ) ? expf(lrow[jj] - m) * inv : 0.f;
}

// out[n, t, ptr[n,s]] += (1-p_gen[tn]) * attn[tn,s] for all t,n,s
__global__ __launch_bounds__(256) void scatterall_kernel(const int* __restrict__ ptr,
                                                         const float* __restrict__ attn,
                                                         const float* __restrict__ pgenall,
                                                         float* __restrict__ out) {
    int f = blockIdx.x * 256 + threadIdx.x;
    if (f >= TDD * NB * SRC) return;
    int tn = f / SRC;
    int s = f - tn * SRC;
    int t = tn / NB, n = tn % NB;
    float w = (1.f - pgenall[tn]) * attn[f];
    atomicAdd(&out[(size_t)(n * TDD + t) * VE + ptr[n * SRC + s]], w);
}

extern "C" void kernel_launch(void* const* d_in, const int* in_sizes, int n_in,
                              void* d_out, int out_size, void* d_ws, size_t ws_size,
                              hipStream_t stream) {
    const int*   src_ids  = (const int*)d_in[0];
    const float* src_mask = (const float*)d_in[1];
    const int*   trg_ids  = (const int*)d_in[2];
    const int*   ptr_idx  = (const int*)d_in[3];
    const float* embed    = (const float*)d_in[4];
    const float* Wih_f = (const float*)d_in[5];
    const float* Whh_f = (const float*)d_in[6];
    const float* bih_f = (const float*)d_in[7];
    const float* bhh_f = (const float*)d_in[8];
    const float* Wih_b = (const float*)d_in[9];
    const float* Whh_b = (const float*)d_in[10];
    const float* bih_b = (const float*)d_in[11];
    const float* bhh_b = (const float*)d_in[12];
    const float* Wih_d = (const float*)d_in[13];
    const float* Whh_d = (const float*)d_in[14];
    const float* bih_d = (const float*)d_in[15];
    const float* bhh_d = (const float*)d_in[16];
    const float* Wk    = (const float*)d_in[17];
    const float* Wd    = (const float*)d_in[18];
    const float* battn = (const float*)d_in[19];
    const float* vvec  = (const float*)d_in[20];
    const float* W1    = (const float*)d_in[21];
    const float* b1    = (const float*)d_in[22];
    const float* W2    = (const float*)d_in[23];
    const float* b2    = (const float*)d_in[24];
    const float* Wp    = (const float*)d_in[25];
    const float* bp    = (const float*)d_in[26];
    float* out = (float*)d_out;

    float* w = (float*)d_ws;
    float* WihTf = w; w += 256 * G3;
    float* WihTb = w; w += 256 * G3;
    float* WihTd = w; w += 256 * G3;
    float* giF = w; w += (size_t)SRC * NB * G3;   // dead after enc_scan
    float* giB = w; w += (size_t)SRC * NB * G3;   // dead after enc_scan
    float* giD = w; w += (size_t)SRC * NB * G3;   // oversize alloc, only TDD used
    float* enc = w; w += (size_t)NB * SRC * 1024;
    float* kp  = w; w += (size_t)NB * SRC * 512;
    float* hF0 = w; w += NB * HE;
    float* hF1 = w; w += NB * HE;
    float* hB0 = w; w += NB * HE;
    float* hB1 = w; w += NB * HE;
    float* h0d = w; w += NB * HD;
    float* hDs = w; w += (size_t)TDD * NB * HD;     // bypass shadow
    float* hD_all = w; w += (size_t)TDD * NB * HD;  // normal copy for downstream
    float* q_all  = w; w += (size_t)TDD * NB * 512;
    float* e_all  = w; w += (size_t)TDD * NB * SRC;
    float* ctx_all = w; w += (size_t)TDD * NB * 1024;
    float* hid1_all = w; w += (size_t)TDD * NB * 512;
    float* pgen_all = w; w += 1024;
    unsigned int* encflag = (unsigned int*)w; w += 2 * SRC * 128;
    unsigned int* decflag = (unsigned int*)w; w += TDD * 128;
    // logits_all (960*50000 = 48M floats) aliases giF..giD region (dead by then)
    float* logits_all = giF;

    // ---- weight transposes (WihT x3 for gi) ----
    transpose_kernel<<<(G3 * 256 + 255) / 256, 256, 0, stream>>>(Wih_f, WihTf, G3, 256);
    transpose_kernel<<<(G3 * 256 + 255) / 256, 256, 0, stream>>>(Wih_b, WihTb, G3, 256);
    transpose_kernel<<<(G3 * 256 + 255) / 256, 256, 0, stream>>>(Wih_d, WihTd, G3, 256);

    // ---- input-gate precompute ----
    gi_kernel<<<dim3(SRC * NB / 16, 6), 256, 0, stream>>>(src_ids, embed, WihTf, bih_f, giF, SRC);
    gi_kernel<<<dim3(SRC * NB / 16, 6), 256, 0, stream>>>(src_ids, embed, WihTb, bih_b, giB, SRC);
    gi_kernel<<<dim3(TDD * NB / 16, 6), 256, 0, stream>>>(trg_ids, embed, WihTd, bih_d, giD, TDD);

    hipMemsetAsync(hF0, 0, NB * HE * sizeof(float), stream);
    hipMemsetAsync(hB0, 0, NB * HE * sizeof(float), stream);
    hipMemsetAsync(h0d, 0, NB * HD * sizeof(float), stream);
    hipMemsetAsync(encflag, 0, (2 * SRC * 128 + TDD * 128) * sizeof(unsigned int), stream);

    // ---- encoder scan: 256 blocks (128/dir), partial flag barrier ----
    enc_scan_kernel<<<dim3(128, 2), 512, 0, stream>>>(
        giF, giB, Whh_f, Whh_b, bhh_f, bhh_b,
        hF0, hF1, hB0, hB1, enc, encflag);

    keyproj_kernel<<<NB * SRC / 8, 256, 0, stream>>>(enc, Wk, kp);

    // ---- decoder recurrence: 128 blocks, 30 steps ----
    dec_scan_kernel<<<128, 512, 0, stream>>>(giD, Whh_d, bhh_d, h0d, hDs, hD_all, decflag);

    // ---- fully batched decoder head over all 30 steps ----
    qall_kernel<<<dim3(TDD * NB / 8, 2), 256, 0, stream>>>(hD_all, Wd, battn, q_all);
    escoreall_kernel<<<TDD * NB * SRC / 4, 256, 0, stream>>>(kp, q_all, vvec, src_mask, e_all);
    softmaxS_kernel<<<TDD * NB, 256, 0, stream>>>(e_all);
    ctxall_kernel<<<dim3(NB, 4), 256, 0, stream>>>(e_all, enc, ctx_all);
    pgenall_kernel<<<TDD * NB, 256, 0, stream>>>(trg_ids, embed, ctx_all, hD_all, Wp, bp, pgen_all);
    hid1all_kernel<<<dim3(TDD * NB / 8, 2), 256, 0, stream>>>(hD_all, ctx_all, W1, b1, hid1_all);
    logitsall_kernel<<<dim3((VSZ + 1023) / 1024, TDD * NB / 48), 512, 0, stream>>>(hid1_all, W2, b2, logits_all);
    outall_kernel<<<TDD * NB, 1024, 0, stream>>>(logits_all, pgen_all, out);
    scatterall_kernel<<<(TDD * NB * SRC + 255) / 256, 256, 0, stream>>>(ptr_idx, e_all, pgen_all, out);
}

// Round 7
// 8876.766 us; speedup vs baseline: 1.8553x; 1.4675x over previous
//
#include <hip/hip_runtime.h>
#include <math.h>

#define VSZ 50000
#define OOVN 50
#define VE 50050
#define EMB 256
#define HE 512
#define HD 512
#define NB 32
#define SRC 400
#define TDD 30
#define G3 1536   // 3*HE = 3*HD

__device__ __forceinline__ float sigmf(float x) { return 1.f / (1.f + expf(-x)); }

// out[c*rows + r] = in[r*cols + c]
__global__ __launch_bounds__(256) void transpose_kernel(const float* __restrict__ in,
                                                        float* __restrict__ out,
                                                        int rows, int cols) {
    int idx = blockIdx.x * 256 + threadIdx.x;
    if (idx >= rows * cols) return;
    int r = idx / cols, c = idx % cols;
    out[c * rows + r] = in[idx];
}

// gi[(s*NB+n)*G3 + c] = bih[c] + sum_e embed[ids[n*steps+s]][e] * WihT[e*G3+c]
__global__ __launch_bounds__(256) void gi_kernel(const int* __restrict__ ids,
                                                 const float* __restrict__ embed,
                                                 const float* __restrict__ WihT,
                                                 const float* __restrict__ bih,
                                                 float* __restrict__ gi, int steps) {
    __shared__ float sx[16][EMB];
    __shared__ int stok[16];
    int tid = threadIdx.x;
    int g0 = blockIdx.x * 16;
    if (tid < 16) {
        int row = g0 + tid;
        int s = row / NB, n = row % NB;
        stok[tid] = ids[n * steps + s];
    }
    __syncthreads();
    for (int r = 0; r < 16; ++r) sx[r][tid] = embed[(size_t)stok[r] * EMB + tid];
    __syncthreads();
    int c = blockIdx.y * 256 + tid;
    float b = bih[c];
    float acc[16];
#pragma unroll
    for (int r = 0; r < 16; ++r) acc[r] = b;
    for (int e = 0; e < EMB; e += 4) {
        float w0 = WihT[(size_t)(e + 0) * G3 + c];
        float w1 = WihT[(size_t)(e + 1) * G3 + c];
        float w2 = WihT[(size_t)(e + 2) * G3 + c];
        float w3 = WihT[(size_t)(e + 3) * G3 + c];
#pragma unroll
        for (int r = 0; r < 16; ++r) {
            float4 x4 = *(const float4*)&sx[r][e];
            acc[r] += x4.x * w0 + x4.y * w1 + x4.z * w2 + x4.w * w3;
        }
    }
#pragma unroll
    for (int r = 0; r < 16; ++r) gi[(size_t)(g0 + r) * G3 + c] = acc[r];
}

// ---------------- persistent encoder scan: L1-safe 4-j blocks, Q=2 oversubscribe ----
// grid (256, 2): y = dir; x: p = bid>>1 (j-slice of 4), q = bid&1 (16-sample group).
// 512 blocks total -> 2 blocks/CU; co-resident blocks are in different q groups so
// one computes while the other spins (barrier latency hidden by oversubscription).
// 512 thr: jl=tid&3, kh=(tid>>2)&15 (k-chunk of 32), ng=tid>>6 (2 samples each).
// Weights/block = 4j x 3 x 512 x 4B = 24.6 KB (L1-resident). Partial barrier: 128
// same-(dir,q) flags only (reads AND WAR stay within the group).
__global__ __launch_bounds__(512) void enc_scan_kernel(
    const float* __restrict__ giF, const float* __restrict__ giB,
    const float* __restrict__ WhhF, const float* __restrict__ WhhB,
    const float* __restrict__ bhhF, const float* __restrict__ bhhB,
    float* __restrict__ hF0, float* __restrict__ hF1,
    float* __restrict__ hB0, float* __restrict__ hB1,
    float* __restrict__ enc, unsigned int* __restrict__ flags) {
    const int z = blockIdx.y;
    const int bid = blockIdx.x;
    const int p = bid >> 1, q = bid & 1;
    const int j0 = p * 4, n0 = q * 16;
    const float* gi  = z ? giB : giF;
    const float* Whh = z ? WhhB : WhhF;
    const float* bhh = z ? bhhB : bhhF;
    float* hbuf[2];
    hbuf[0] = z ? hB0 : hF0;
    hbuf[1] = z ? hB1 : hF1;
    unsigned int* fl = flags + (size_t)z * SRC * 256;

    __shared__ float hlds[16 * 576];   // [nloc][kh*36 + i]  36.9 KB -> 2 blocks/CU

    const int tid = threadIdx.x;
    const int jl = tid & 3;
    const int kh = (tid >> 2) & 15;
    const int ng = tid >> 6;           // 0..7, two samples each
    const int j = j0 + jl;
    const int kbase = kh * 36;

    const float bR = bhh[j], bZ = bhh[512 + j], bN = bhh[1024 + j];
    const float* wR = Whh + (size_t)(0 * 512 + j) * 512 + kh * 32;
    const float* wZ = Whh + (size_t)(1 * 512 + j) * 512 + kh * 32;
    const float* wN = Whh + (size_t)(2 * 512 + j) * 512 + kh * 32;

    for (int t = 0; t < SRC; ++t) {
        const int s = z ? (SRC - 1 - t) : t;
        const float* hin = hbuf[t & 1];
        float* hout = hbuf[(t + 1) & 1];

        // gi prefetch (2 samples x 3 gates) -- latency hides under staging+compute
        float gpre[6];
        if (kh == 0) {
#pragma unroll
            for (int r = 0; r < 2; ++r) {
                int n = n0 + ng * 2 + r;
                const float* gir = gi + (size_t)(s * NB + n) * G3 + j;
                gpre[r * 3 + 0] = gir[0];
                gpre[r * 3 + 1] = gir[512];
                gpre[r * 3 + 2] = gir[1024];
            }
        }

        // stage this group's 16 h-rows (32 KB) via 8B bypass loads
        const unsigned long long* hin8 = (const unsigned long long*)(hin + n0 * 512);
        for (int idx = tid; idx < 16 * 256; idx += 512) {
            unsigned long long uv = __hip_atomic_load(&hin8[idx], __ATOMIC_RELAXED,
                                                      __HIP_MEMORY_SCOPE_AGENT);
            union { unsigned long long u; float f[2]; } cv; cv.u = uv;
            int nn = idx >> 8, kk = (idx & 255) << 1;
            int off = nn * 576 + (kk >> 5) * 36 + (kk & 31);
            hlds[off] = cv.f[0];
            hlds[off + 1] = cv.f[1];
        }
        __syncthreads();

        float aR[2] = {0.f, 0.f}, aZ[2] = {0.f, 0.f}, aN[2] = {0.f, 0.f};
        const float* h0p = &hlds[(ng * 2 + 0) * 576 + kbase];
        const float* h1p = &hlds[(ng * 2 + 1) * 576 + kbase];
#pragma unroll
        for (int i = 0; i < 32; i += 4) {
            float4 wr = *(const float4*)&wR[i];
            float4 wz = *(const float4*)&wZ[i];
            float4 wn = *(const float4*)&wN[i];
            float4 ha = *(const float4*)&h0p[i];
            float4 hb = *(const float4*)&h1p[i];
            aR[0] += ha.x*wr.x + ha.y*wr.y + ha.z*wr.z + ha.w*wr.w;
            aZ[0] += ha.x*wz.x + ha.y*wz.y + ha.z*wz.z + ha.w*wz.w;
            aN[0] += ha.x*wn.x + ha.y*wn.y + ha.z*wn.z + ha.w*wn.w;
            aR[1] += hb.x*wr.x + hb.y*wr.y + hb.z*wr.z + hb.w*wr.w;
            aZ[1] += hb.x*wz.x + hb.y*wz.y + hb.z*wz.z + hb.w*wz.w;
            aN[1] += hb.x*wn.x + hb.y*wn.y + hb.z*wn.z + hb.w*wn.w;
        }
        // reduce over kh (tid bits 2..5, within the 64-lane wave)
#pragma unroll
        for (int r = 0; r < 2; ++r) {
            aR[r] += __shfl_xor(aR[r], 4);  aR[r] += __shfl_xor(aR[r], 8);
            aR[r] += __shfl_xor(aR[r], 16); aR[r] += __shfl_xor(aR[r], 32);
            aZ[r] += __shfl_xor(aZ[r], 4);  aZ[r] += __shfl_xor(aZ[r], 8);
            aZ[r] += __shfl_xor(aZ[r], 16); aZ[r] += __shfl_xor(aZ[r], 32);
            aN[r] += __shfl_xor(aN[r], 4);  aN[r] += __shfl_xor(aN[r], 8);
            aN[r] += __shfl_xor(aN[r], 16); aN[r] += __shfl_xor(aN[r], 32);
        }
        if (kh == 0) {
#pragma unroll
            for (int r = 0; r < 2; ++r) {
                int nloc = ng * 2 + r;
                int n = n0 + nloc;
                float rr  = sigmf(gpre[r * 3 + 0] + bR + aR[r]);
                float zz  = sigmf(gpre[r * 3 + 1] + bZ + aZ[r]);
                float nn2 = tanhf(gpre[r * 3 + 2] + bN + rr * aN[r]);
                float hp  = hlds[nloc * 576 + (j >> 5) * 36 + (j & 31)];
                float hnew = (1.f - zz) * nn2 + zz * hp;
                __hip_atomic_store(&hout[n * 512 + j], hnew, __ATOMIC_RELAXED,
                                   __HIP_MEMORY_SCOPE_AGENT);
                enc[(size_t)(n * SRC + s) * 1024 + z * 512 + j] = hnew;
            }
        }
        __syncthreads();   // per-wave store drain before flag
        if (tid == 0)
            __hip_atomic_store(&fl[t * 256 + q * 128 + p], 1u, __ATOMIC_RELAXED,
                               __HIP_MEMORY_SCOPE_AGENT);
        if (t != SRC - 1) {
            // partial barrier: only the 128 same-(dir,q) producers matter
            if (tid < 64) {
                const unsigned int* ft = fl + t * 256 + q * 128;
                for (;;) {
                    unsigned int a = __hip_atomic_load(&ft[tid], __ATOMIC_RELAXED,
                                                       __HIP_MEMORY_SCOPE_AGENT);
                    unsigned int b = __hip_atomic_load(&ft[64 + tid], __ATOMIC_RELAXED,
                                                       __HIP_MEMORY_SCOPE_AGENT);
                    if (__all(a != 0u && b != 0u)) break;
                    __builtin_amdgcn_s_sleep(1);
                }
            }
            __syncthreads();
        }
    }
}

// ---------------- persistent decoder recurrence (round-4 structure, 128 blocks) ----
__global__ __launch_bounds__(512) void dec_scan_kernel(
    const float* __restrict__ gi, const float* __restrict__ Whh,
    const float* __restrict__ bhh, const float* __restrict__ h0,
    float* __restrict__ hDs, float* __restrict__ hD_all,
    unsigned int* __restrict__ flags) {
    const int b1 = blockIdx.x;
    const int j0 = b1 * 4;
    __shared__ float hlds[32 * 576];
    const int tid = threadIdx.x;
    const int jl = tid & 3;
    const int kh = (tid >> 2) & 15;
    const int ng = tid >> 6;
    const int j  = j0 + jl;
    const int kbase = kh * 36;

    const float bR = bhh[j], bZ = bhh[512 + j], bN = bhh[1024 + j];
    const float* wR = Whh + (size_t)(0 * 512 + j) * 512 + kh * 32;
    const float* wZ = Whh + (size_t)(1 * 512 + j) * 512 + kh * 32;
    const float* wN = Whh + (size_t)(2 * 512 + j) * 512 + kh * 32;

    for (int t = 0; t < TDD; ++t) {
        const float* hin = t ? (hDs + (size_t)(t - 1) * NB * 512) : h0;
        float* hout = hDs + (size_t)t * NB * 512;

        float gpre[12];
        if (kh == 0) {
#pragma unroll
            for (int r = 0; r < 4; ++r) {
                const float* gir = gi + (size_t)(t * NB + ng * 4 + r) * G3 + j;
                gpre[r * 3 + 0] = gir[0];
                gpre[r * 3 + 1] = gir[512];
                gpre[r * 3 + 2] = gir[1024];
            }
        }

        const unsigned long long* hin8 = (const unsigned long long*)hin;
        for (int idx = tid; idx < 32 * 256; idx += 512) {
            unsigned long long uv = __hip_atomic_load(&hin8[idx], __ATOMIC_RELAXED,
                                                      __HIP_MEMORY_SCOPE_AGENT);
            union { unsigned long long u; float f[2]; } cv; cv.u = uv;
            int nn = idx >> 8, kk = (idx & 255) << 1;
            int off = nn * 576 + (kk >> 5) * 36 + (kk & 31);
            hlds[off] = cv.f[0];
            hlds[off + 1] = cv.f[1];
        }
        __syncthreads();

        float aR[4] = {0.f, 0.f, 0.f, 0.f};
        float aZ[4] = {0.f, 0.f, 0.f, 0.f};
        float aN[4] = {0.f, 0.f, 0.f, 0.f};
        const float* h0p = &hlds[(ng * 4 + 0) * 576 + kbase];
        const float* h1p = &hlds[(ng * 4 + 1) * 576 + kbase];
        const float* h2p = &hlds[(ng * 4 + 2) * 576 + kbase];
        const float* h3p = &hlds[(ng * 4 + 3) * 576 + kbase];
#pragma unroll
        for (int i = 0; i < 32; i += 4) {
            float4 wr = *(const float4*)&wR[i];
            float4 wz = *(const float4*)&wZ[i];
            float4 wn = *(const float4*)&wN[i];
            float4 ha = *(const float4*)&h0p[i];
            float4 hb = *(const float4*)&h1p[i];
            float4 hc = *(const float4*)&h2p[i];
            float4 hd = *(const float4*)&h3p[i];
            aR[0] += ha.x*wr.x + ha.y*wr.y + ha.z*wr.z + ha.w*wr.w;
            aZ[0] += ha.x*wz.x + ha.y*wz.y + ha.z*wz.z + ha.w*wz.w;
            aN[0] += ha.x*wn.x + ha.y*wn.y + ha.z*wn.z + ha.w*wn.w;
            aR[1] += hb.x*wr.x + hb.y*wr.y + hb.z*wr.z + hb.w*wr.w;
            aZ[1] += hb.x*wz.x + hb.y*wz.y + hb.z*wz.z + hb.w*wz.w;
            aN[1] += hb.x*wn.x + hb.y*wn.y + hb.z*wn.z + hb.w*wn.w;
            aR[2] += hc.x*wr.x + hc.y*wr.y + hc.z*wr.z + hc.w*wr.w;
            aZ[2] += hc.x*wz.x + hc.y*wz.y + hc.z*wz.z + hc.w*wz.w;
            aN[2] += hc.x*wn.x + hc.y*wn.y + hc.z*wn.z + hc.w*wn.w;
            aR[3] += hd.x*wr.x + hd.y*wr.y + hd.z*wr.z + hd.w*wr.w;
            aZ[3] += hd.x*wz.x + hd.y*wz.y + hd.z*wz.z + hd.w*wz.w;
            aN[3] += hd.x*wn.x + hd.y*wn.y + hd.z*wn.z + hd.w*wn.w;
        }
#pragma unroll
        for (int r = 0; r < 4; ++r) {
            aR[r] += __shfl_xor(aR[r], 4);  aR[r] += __shfl_xor(aR[r], 8);
            aR[r] += __shfl_xor(aR[r], 16); aR[r] += __shfl_xor(aR[r], 32);
            aZ[r] += __shfl_xor(aZ[r], 4);  aZ[r] += __shfl_xor(aZ[r], 8);
            aZ[r] += __shfl_xor(aZ[r], 16); aZ[r] += __shfl_xor(aZ[r], 32);
            aN[r] += __shfl_xor(aN[r], 4);  aN[r] += __shfl_xor(aN[r], 8);
            aN[r] += __shfl_xor(aN[r], 16); aN[r] += __shfl_xor(aN[r], 32);
        }
        if (kh == 0) {
#pragma unroll
            for (int r = 0; r < 4; ++r) {
                int n = ng * 4 + r;
                float rr  = sigmf(gpre[r * 3 + 0] + bR + aR[r]);
                float zz  = sigmf(gpre[r * 3 + 1] + bZ + aZ[r]);
                float nn2 = tanhf(gpre[r * 3 + 2] + bN + rr * aN[r]);
                float hp  = hlds[n * 576 + (j >> 5) * 36 + (j & 31)];
                float hnew = (1.f - zz) * nn2 + zz * hp;
                __hip_atomic_store(&hout[n * 512 + j], hnew, __ATOMIC_RELAXED,
                                   __HIP_MEMORY_SCOPE_AGENT);
                hD_all[(size_t)t * NB * 512 + n * 512 + j] = hnew;
            }
        }
        __syncthreads();
        if (tid == 0)
            __hip_atomic_store(&flags[t * 128 + b1], 1u, __ATOMIC_RELAXED,
                               __HIP_MEMORY_SCOPE_AGENT);
        if (t != TDD - 1) {
            if (tid < 64) {
                const unsigned int* ft = flags + t * 128;
                for (;;) {
                    unsigned int a = __hip_atomic_load(&ft[tid], __ATOMIC_RELAXED,
                                                       __HIP_MEMORY_SCOPE_AGENT);
                    unsigned int b = __hip_atomic_load(&ft[64 + tid], __ATOMIC_RELAXED,
                                                       __HIP_MEMORY_SCOPE_AGENT);
                    if (__all(a != 0u && b != 0u)) break;
                    __builtin_amdgcn_s_sleep(1);
                }
            }
            __syncthreads();
        }
    }
}

// key_proj J=2: kp[row*512 + c] = sum_k enc[row][k]*Wk[k*512+c]; 8 rows/block, grid 1600
__global__ __launch_bounds__(256) void keyproj_kernel(const float* __restrict__ enc,
                                                      const float* __restrict__ Wk,
                                                      float* __restrict__ kp) {
    __shared__ float sx[8][1024];
    int tid = threadIdx.x;
    int g0 = blockIdx.x * 8;
    for (int i = tid; i < 8 * 1024; i += 256)
        sx[i >> 10][i & 1023] = enc[(size_t)(g0 + (i >> 10)) * 1024 + (i & 1023)];
    __syncthreads();
    int c = tid * 2;
    float acc[8][2];
#pragma unroll
    for (int r = 0; r < 8; ++r) { acc[r][0] = 0.f; acc[r][1] = 0.f; }
    for (int k = 0; k < 1024; k += 4) {
        float2 w0 = *(const float2*)&Wk[(size_t)(k + 0) * 512 + c];
        float2 w1 = *(const float2*)&Wk[(size_t)(k + 1) * 512 + c];
        float2 w2 = *(const float2*)&Wk[(size_t)(k + 2) * 512 + c];
        float2 w3 = *(const float2*)&Wk[(size_t)(k + 3) * 512 + c];
#pragma unroll
        for (int r = 0; r < 8; ++r) {
            float4 x4 = *(const float4*)&sx[r][k];
            acc[r][0] += x4.x * w0.x + x4.y * w1.x + x4.z * w2.x + x4.w * w3.x;
            acc[r][1] += x4.x * w0.y + x4.y * w1.y + x4.z * w2.y + x4.w * w3.y;
        }
    }
#pragma unroll
    for (int r = 0; r < 8; ++r)
        *(float2*)&kp[(size_t)(g0 + r) * 512 + c] = make_float2(acc[r][0], acc[r][1]);
}

// q_all[tn][c] = battn[c] + hD_all[tn] . Wd[:,c]; 8 rows/block, grid (120,2)
__global__ __launch_bounds__(256) void qall_kernel(const float* __restrict__ hall,
                                                   const float* __restrict__ Wd,
                                                   const float* __restrict__ battn,
                                                   float* __restrict__ qall) {
    __shared__ float sx[8][512];
    int tid = threadIdx.x;
    int g0 = blockIdx.x * 8;
    for (int i = tid; i < 8 * 512; i += 256)
        sx[i >> 9][i & 511] = hall[(size_t)(g0 + (i >> 9)) * 512 + (i & 511)];
    __syncthreads();
    int c = blockIdx.y * 256 + tid;
    float b = battn[c];
    float acc[8];
#pragma unroll
    for (int r = 0; r < 8; ++r) acc[r] = b;
    for (int k = 0; k < 512; k += 4) {
        float w0 = Wd[(size_t)(k + 0) * 512 + c];
        float w1 = Wd[(size_t)(k + 1) * 512 + c];
        float w2 = Wd[(size_t)(k + 2) * 512 + c];
        float w3 = Wd[(size_t)(k + 3) * 512 + c];
#pragma unroll
        for (int r = 0; r < 8; ++r) {
            float4 x4 = *(const float4*)&sx[r][k];
            acc[r] += x4.x * w0 + x4.y * w1 + x4.z * w2 + x4.w * w3;
        }
    }
#pragma unroll
    for (int r = 0; r < 8; ++r) qall[(size_t)(g0 + r) * 512 + c] = acc[r];
}

// e_all[(tn)*SRC+s] = v . tanh(kp[n,s,:] + q_all[tn]) + mask ; 4 rows/block
__global__ __launch_bounds__(256) void escoreall_kernel(const float* __restrict__ kp,
                                                        const float* __restrict__ qall,
                                                        const float* __restrict__ vvec,
                                                        const float* __restrict__ mask,
                                                        float* __restrict__ e) {
    __shared__ float sq[512];
    int tid = threadIdx.x;
    int row0 = blockIdx.x * 4;
    int tn = row0 / SRC;
    int n = tn % NB;
    sq[tid] = qall[(size_t)tn * 512 + tid];
    sq[256 + tid] = qall[(size_t)tn * 512 + 256 + tid];
    __syncthreads();
    int w = tid >> 6, lane = tid & 63;
    int row = row0 + w;
    int s = row % SRC;
    const float* kpr = kp + (size_t)(n * SRC + s) * 512;
    float acc = 0.f;
#pragma unroll
    for (int i = 0; i < 8; ++i) {
        int d = lane + i * 64;
        acc += vvec[d] * tanhf(kpr[d] + sq[d]);
    }
    for (int off = 32; off; off >>= 1) acc += __shfl_down(acc, off, 64);
    if (lane == 0) e[row] = acc + (1.f - mask[n * SRC + s]) * (-1e10f);
}

// softmax over SRC per row, in place. block per row.
__global__ __launch_bounds__(256) void softmaxS_kernel(float* __restrict__ e) {
    __shared__ float red[256];
    int n = blockIdx.x, tid = threadIdx.x;
    float* row = e + (size_t)n * SRC;
    float m = -3.4e38f;
    for (int s = tid; s < SRC; s += 256) m = fmaxf(m, row[s]);
    red[tid] = m; __syncthreads();
    for (int off = 128; off; off >>= 1) { if (tid < off) red[tid] = fmaxf(red[tid], red[tid + off]); __syncthreads(); }
    m = red[0]; __syncthreads();
    float sum = 0.f;
    for (int s = tid; s < SRC; s += 256) sum += expf(row[s] - m);
    red[tid] = sum; __syncthreads();
    for (int off = 128; off; off >>= 1) { if (tid < off) red[tid] += red[tid + off]; __syncthreads(); }
    float inv = 1.f / red[0]; __syncthreads();
    for (int s = tid; s < SRC; s += 256) row[s] = expf(row[s] - m) * inv;
}

// ctx_all[(t*NB+n)*1024+d] = sum_s attn[(t*NB+n)*SRC+s]*enc[n,s,d]; grid (32,4)
__global__ __launch_bounds__(256) void ctxall_kernel(const float* __restrict__ attn,
                                                     const float* __restrict__ enc,
                                                     float* __restrict__ ctxall) {
    __shared__ float sa[TDD * SRC];   // 48 KB
    int n = blockIdx.x, tid = threadIdx.x;
    for (int i = tid; i < TDD * SRC; i += 256) {
        int t = i / SRC, s = i - t * SRC;
        sa[i] = attn[(size_t)(t * NB + n) * SRC + s];
    }
    __syncthreads();
    int d = blockIdx.y * 256 + tid;
    const float* er = enc + (size_t)n * SRC * 1024 + d;
    float acc[TDD];
#pragma unroll
    for (int t = 0; t < TDD; ++t) acc[t] = 0.f;
    for (int s = 0; s < SRC; s += 4) {
        float e0 = er[(size_t)(s + 0) * 1024];
        float e1 = er[(size_t)(s + 1) * 1024];
        float e2 = er[(size_t)(s + 2) * 1024];
        float e3 = er[(size_t)(s + 3) * 1024];
#pragma unroll
        for (int t = 0; t < TDD; ++t) {
            float4 a4 = *(const float4*)&sa[t * SRC + s];
            acc[t] += a4.x * e0 + a4.y * e1 + a4.z * e2 + a4.w * e3;
        }
    }
#pragma unroll
    for (int t = 0; t < TDD; ++t) ctxall[(size_t)(t * NB + n) * 1024 + d] = acc[t];
}

// pgen_all[tn] = sigmoid([xi, ctx, h] . Wp + bp); block per tn, grid 960
__global__ __launch_bounds__(256) void pgenall_kernel(const int* __restrict__ trg_ids,
                                                      const float* __restrict__ embed,
                                                      const float* __restrict__ ctxall,
                                                      const float* __restrict__ hall,
                                                      const float* __restrict__ Wp,
                                                      const float* __restrict__ bp,
                                                      float* __restrict__ pgenall) {
    __shared__ float red[256];
    int tn = blockIdx.x, tid = threadIdx.x;
    int t = tn / NB, n = tn % NB;
    int tok = trg_ids[n * TDD + t];
    float acc = 0.f;
    for (int i = tid; i < 1792; i += 256) {
        float val;
        if (i < 256) val = embed[(size_t)tok * EMB + i];
        else if (i < 1280) val = ctxall[(size_t)tn * 1024 + (i - 256)];
        else val = hall[(size_t)tn * 512 + (i - 1280)];
        acc += val * Wp[i];
    }
    red[tid] = acc; __syncthreads();
    for (int off = 128; off; off >>= 1) { if (tid < off) red[tid] += red[tid + off]; __syncthreads(); }
    if (tid == 0) pgenall[tn] = 1.f / (1.f + expf(-(red[0] + bp[0])));
}

// hid1_all[tn][c] = b1[c] + [h,ctx] . W1[:,c]; 8 rows/block, grid (120,2)
__global__ __launch_bounds__(256) void hid1all_kernel(const float* __restrict__ hall,
                                                      const float* __restrict__ ctxall,
                                                      const float* __restrict__ W1,
                                                      const float* __restrict__ b1,
                                                      float* __restrict__ hid1all) {
    __shared__ float sc[8][1536];   // 48 KB
    int tid = threadIdx.x;
    int g0 = blockIdx.x * 8;
    for (int i = tid; i < 8 * 512; i += 256)
        sc[i >> 9][i & 511] = hall[(size_t)(g0 + (i >> 9)) * 512 + (i & 511)];
    for (int i = tid; i < 8 * 1024; i += 256)
        sc[i >> 10][512 + (i & 1023)] = ctxall[(size_t)(g0 + (i >> 10)) * 1024 + (i & 1023)];
    __syncthreads();
    int c = blockIdx.y * 256 + tid;
    float acc[8];
    float b = b1[c];
#pragma unroll
    for (int r = 0; r < 8; ++r) acc[r] = b;
    for (int k = 0; k < 1536; k += 4) {
        float w0 = W1[(size_t)(k + 0) * 512 + c];
        float w1 = W1[(size_t)(k + 1) * 512 + c];
        float w2 = W1[(size_t)(k + 2) * 512 + c];
        float w3 = W1[(size_t)(k + 3) * 512 + c];
#pragma unroll
        for (int r = 0; r < 8; ++r) {
            float4 x4 = *(const float4*)&sc[r][k];
            acc[r] += x4.x * w0 + x4.y * w1 + x4.z * w2 + x4.w * w3;
        }
    }
#pragma unroll
    for (int r = 0; r < 8; ++r) hid1all[(size_t)(g0 + r) * 512 + c] = acc[r];
}

// logits: 48 rows/block, J=2 j/thread, 512 thr. grid (49, 20). W2 re-read 20x only.
__global__ __launch_bounds__(512) void logitsall_kernel(const float* __restrict__ hid1,
                                                        const float* __restrict__ W2,
                                                        const float* __restrict__ b2,
                                                        float* __restrict__ logits) {
    __shared__ float sh[48][512];   // 96 KB
    int tid = threadIdx.x;
    int r0 = blockIdx.y * 48;
    for (int i = tid; i < 48 * 512; i += 512) sh[i >> 9][i & 511] = hid1[(size_t)r0 * 512 + i];
    __syncthreads();
    int j = blockIdx.x * 1024 + tid * 2;
    if (j >= VSZ) return;
    float acc[48][2];
#pragma unroll
    for (int r = 0; r < 48; ++r) { acc[r][0] = 0.f; acc[r][1] = 0.f; }
    for (int k = 0; k < 512; k += 2) {
        float2 w0 = *(const float2*)&W2[(size_t)(k + 0) * VSZ + j];
        float2 w1 = *(const float2*)&W2[(size_t)(k + 1) * VSZ + j];
#pragma unroll
        for (int r = 0; r < 48; ++r) {
            float2 h2 = *(const float2*)&sh[r][k];
            acc[r][0] += h2.x * w0.x + h2.y * w1.x;
            acc[r][1] += h2.x * w0.y + h2.y * w1.y;
        }
    }
    float2 bb = *(const float2*)&b2[j];
#pragma unroll
    for (int r = 0; r < 48; ++r) {
        float2 o; o.x = acc[r][0] + bb.x; o.y = acc[r][1] + bb.y;
        *(float2*)&logits[(size_t)(r0 + r) * VSZ + j] = o;
    }
}

// softmax over V, scale by p_gen, write out row; block per tn
__global__ __launch_bounds__(1024) void outall_kernel(const float* __restrict__ logits,
                                                      const float* __restrict__ pgenall,
                                                      float* __restrict__ out) {
    __shared__ float red[1024];
    int tn = blockIdx.x, tid = threadIdx.x;
    int t = tn / NB, n = tn % NB;
    const float* lrow = logits + (size_t)tn * VSZ;
    float m = -3.4e38f;
    for (int jj = tid; jj < VSZ; jj += 1024) m = fmaxf(m, lrow[jj]);
    red[tid] = m; __syncthreads();
    for (int off = 512; off; off >>= 1) { if (tid < off) red[tid] = fmaxf(red[tid], red[tid + off]); __syncthreads(); }
    m = red[0]; __syncthreads();
    float sum = 0.f;
    for (int jj = tid; jj < VSZ; jj += 1024) sum += expf(lrow[jj] - m);
    red[tid] = sum; __syncthreads();
    for (int off = 512; off; off >>= 1) { if (tid < off) red[tid] += red[tid + off]; __syncthreads(); }
    float inv = pgenall[tn] / red[0];
    float* orow = out + (size_t)(n * TDD + t) * VE;
    for (int jj = tid; jj < VE; jj += 1024) orow[jj] = (jj < VSZ) ? expf(lrow[jj] - m) * inv : 0.f;
}

// out[n, t, ptr[n,s]] += (1-p_gen[tn]) * attn[tn,s] for all t,n,s
__global__ __launch_bounds__(256) void scatterall_kernel(const int* __restrict__ ptr,
                                                         const float* __restrict__ attn,
                                                         const float* __restrict__ pgenall,
                                                         float* __restrict__ out) {
    int f = blockIdx.x * 256 + threadIdx.x;
    if (f >= TDD * NB * SRC) return;
    int tn = f / SRC;
    int s = f - tn * SRC;
    int t = tn / NB, n = tn % NB;
    float w = (1.f - pgenall[tn]) * attn[f];
    atomicAdd(&out[(size_t)(n * TDD + t) * VE + ptr[n * SRC + s]], w);
}

extern "C" void kernel_launch(void* const* d_in, const int* in_sizes, int n_in,
                              void* d_out, int out_size, void* d_ws, size_t ws_size,
                              hipStream_t stream) {
    const int*   src_ids  = (const int*)d_in[0];
    const float* src_mask = (const float*)d_in[1];
    const int*   trg_ids  = (const int*)d_in[2];
    const int*   ptr_idx  = (const int*)d_in[3];
    const float* embed    = (const float*)d_in[4];
    const float* Wih_f = (const float*)d_in[5];
    const float* Whh_f = (const float*)d_in[6];
    const float* bih_f = (const float*)d_in[7];
    const float* bhh_f = (const float*)d_in[8];
    const float* Wih_b = (const float*)d_in[9];
    const float* Whh_b = (const float*)d_in[10];
    const float* bih_b = (const float*)d_in[11];
    const float* bhh_b = (const float*)d_in[12];
    const float* Wih_d = (const float*)d_in[13];
    const float* Whh_d = (const float*)d_in[14];
    const float* bih_d = (const float*)d_in[15];
    const float* bhh_d = (const float*)d_in[16];
    const float* Wk    = (const float*)d_in[17];
    const float* Wd    = (const float*)d_in[18];
    const float* battn = (const float*)d_in[19];
    const float* vvec  = (const float*)d_in[20];
    const float* W1    = (const float*)d_in[21];
    const float* b1    = (const float*)d_in[22];
    const float* W2    = (const float*)d_in[23];
    const float* b2    = (const float*)d_in[24];
    const float* Wp    = (const float*)d_in[25];
    const float* bp    = (const float*)d_in[26];
    float* out = (float*)d_out;

    float* w = (float*)d_ws;
    float* WihTf = w; w += 256 * G3;
    float* WihTb = w; w += 256 * G3;
    float* WihTd = w; w += 256 * G3;
    float* giF = w; w += (size_t)SRC * NB * G3;   // dead after enc_scan
    float* giB = w; w += (size_t)SRC * NB * G3;   // dead after enc_scan
    float* giD = w; w += (size_t)SRC * NB * G3;   // oversize alloc, only TDD used
    float* enc = w; w += (size_t)NB * SRC * 1024;
    float* kp  = w; w += (size_t)NB * SRC * 512;
    float* hF0 = w; w += NB * HE;
    float* hF1 = w; w += NB * HE;
    float* hB0 = w; w += NB * HE;
    float* hB1 = w; w += NB * HE;
    float* h0d = w; w += NB * HD;
    float* hDs = w; w += (size_t)TDD * NB * HD;     // bypass shadow
    float* hD_all = w; w += (size_t)TDD * NB * HD;  // normal copy for downstream
    float* q_all  = w; w += (size_t)TDD * NB * 512;
    float* e_all  = w; w += (size_t)TDD * NB * SRC;
    float* ctx_all = w; w += (size_t)TDD * NB * 1024;
    float* hid1_all = w; w += (size_t)TDD * NB * 512;
    float* pgen_all = w; w += 1024;
    unsigned int* encflag = (unsigned int*)w; w += 2 * SRC * 256;
    unsigned int* decflag = (unsigned int*)w; w += TDD * 128;
    // logits_all (960*50000 = 48M floats) aliases giF..giD region (dead by then)
    float* logits_all = giF;

    // ---- weight transposes (WihT x3 for gi) ----
    transpose_kernel<<<(G3 * 256 + 255) / 256, 256, 0, stream>>>(Wih_f, WihTf, G3, 256);
    transpose_kernel<<<(G3 * 256 + 255) / 256, 256, 0, stream>>>(Wih_b, WihTb, G3, 256);
    transpose_kernel<<<(G3 * 256 + 255) / 256, 256, 0, stream>>>(Wih_d, WihTd, G3, 256);

    // ---- input-gate precompute ----
    gi_kernel<<<dim3(SRC * NB / 16, 6), 256, 0, stream>>>(src_ids, embed, WihTf, bih_f, giF, SRC);
    gi_kernel<<<dim3(SRC * NB / 16, 6), 256, 0, stream>>>(src_ids, embed, WihTb, bih_b, giB, SRC);
    gi_kernel<<<dim3(TDD * NB / 16, 6), 256, 0, stream>>>(trg_ids, embed, WihTd, bih_d, giD, TDD);

    hipMemsetAsync(hF0, 0, NB * HE * sizeof(float), stream);
    hipMemsetAsync(hB0, 0, NB * HE * sizeof(float), stream);
    hipMemsetAsync(h0d, 0, NB * HD * sizeof(float), stream);
    hipMemsetAsync(encflag, 0, (2 * SRC * 256 + TDD * 128) * sizeof(unsigned int), stream);

    // ---- encoder scan: 512 blocks (2/CU oversubscribed), partial flag barrier ----
    enc_scan_kernel<<<dim3(256, 2), 512, 0, stream>>>(
        giF, giB, Whh_f, Whh_b, bhh_f, bhh_b,
        hF0, hF1, hB0, hB1, enc, encflag);

    keyproj_kernel<<<NB * SRC / 8, 256, 0, stream>>>(enc, Wk, kp);

    // ---- decoder recurrence: 128 blocks, 30 steps (round-4 structure) ----
    dec_scan_kernel<<<128, 512, 0, stream>>>(giD, Whh_d, bhh_d, h0d, hDs, hD_all, decflag);

    // ---- fully batched decoder head over all 30 steps ----
    qall_kernel<<<dim3(TDD * NB / 8, 2), 256, 0, stream>>>(hD_all, Wd, battn, q_all);
    escoreall_kernel<<<TDD * NB * SRC / 4, 256, 0, stream>>>(kp, q_all, vvec, src_mask, e_all);
    softmaxS_kernel<<<TDD * NB, 256, 0, stream>>>(e_all);
    ctxall_kernel<<<dim3(NB, 4), 256, 0, stream>>>(e_all, enc, ctx_all);
    pgenall_kernel<<<TDD * NB, 256, 0, stream>>>(trg_ids, embed, ctx_all, hD_all, Wp, bp, pgen_all);
    hid1all_kernel<<<dim3(TDD * NB / 8, 2), 256, 0, stream>>>(hD_all, ctx_all, W1, b1, hid1_all);
    logitsall_kernel<<<dim3((VSZ + 1023) / 1024, TDD * NB / 48), 512, 0, stream>>>(hid1_all, W2, b2, logits_all);
    outall_kernel<<<TDD * NB, 1024, 0, stream>>>(logits_all, pgen_all, out);
    scatterall_kernel<<<(TDD * NB * SRC + 255) / 256, 256, 0, stream>>>(ptr_idx, e_all, pgen_all, out);
}